// Round 4
// baseline (1087.831 us; speedup 1.0000x reference)
//
#include <hip/hip_runtime.h>
#include <hip/hip_bf16.h>

// trackletGNN: 3x edge-conv + MLP head.
// R11: raise memory-level parallelism in the gather loops.
// R10 post-mortem: k_part atomic fix confirmed (dropped out of top-5), but
// eagg l2/l3 stuck at 224us each: FETCH 780MB (~1 line fill/edge), VALU 12%,
// fill rate 3.6TB/s -- NOTHING saturated, VGPR=28 => ~1 outstanding gather
// per thread = MLP-deficit, latency-bound on L3-hit fills (~400-700cy).
// Src-slice sort verdict: didn't produce cross-block lockstep (hA 768->680MB
// only), but DID make the 3MB hB table L2-resident (kept).
// R11: (a) eagg + eagg1 inner loops software-pipelined x4: 4 perm loads +
// 4 hA/hB gathers issued before any compute -> 4x outstanding misses/thread.
// ~28 extra VGPR, still <=64 => 8 blocks/CU preserved. (b) k_mscanA NSEG
// 8->32 (1472 blocks instead of 368) -- was running 34MB through 23K
// threads. Bit-identical math, only issue order changes.

#define NNODES 1500000
#define NEDGES 12000000
#define NTRACK 250000
#define BSH    9           // log2(bucket size)
#define BSZ    512         // nodes per agg bucket
#define BMASK  511u
#define NBUCK  2930        // ceil(NNODES/512)
#define PCHUNK 4096        // edges per k_part block (LDS-sorted)
#define PBLK   2930        // ceil(NEDGES/PCHUNK)
#define NSEG   32          // chunk segments for the column scan
#define SEGC   92          // chunks per segment (32*92 >= 2930)
#define NTILE  46          // bucket tiles of 64 ((2930+63)/64)
#define SRCMASK 0x1FFFFFu  // 21 bits
#define NSLICE 48          // src slices (src>>15, 512KB of hA each)
#define SRTR   20          // k_srt records/thread (covers runs to 5120)
#define FXSCALE 16777216.f // 2^24
#define FXINV   (1.f / 16777216.f)

typedef unsigned int   u32;
typedef unsigned short u16;

static __device__ __forceinline__ float b2f(u32 v) {
    union { float f; u32 u; } x; x.u = v << 16; return x.f;
}
static __device__ __forceinline__ u16 f2b(float f) {
    __hip_bfloat16 h = __float2bfloat16(f);
    return *reinterpret_cast<u16*>(&h);
}
static __device__ __forceinline__ float ldw(const void* p, int i, int isf32) {
    return isf32 ? ((const float*)p)[i] : b2f((u32)((const u16*)p)[i]);
}
static __device__ __forceinline__ int fx(float f) {
    return (int)rintf(f * FXSCALE);
}

// ---------------- dtype probe ----------------

__global__ void k_detect(const u16* a, const u16* b, const u16* c,
                         const u16* d, const u16* e, const u16* f,
                         int* flag) {
    if (blockIdx.x == 0 && threadIdx.x == 0) {
        int isf32 = 0;
        const u16* ps[6] = {a, b, c, d, e, f};
        const int  ns[6] = {9, 9, 9, 9, 9, 8};
        for (int k = 0; k < 6; k++)
            for (int i = 0; i < ns[k]; i++) {
                float v = b2f((u32)ps[k][i]);
                if (!(fabsf(v) < 1.0e3f)) isf32 = 1;   // catches NaN/Inf too
            }
        *flag = isf32;
    }
}

// ------------- x -> bf16 table (3 MB, fits per-XCD L2 for layer 1) -------

__global__ __launch_bounds__(256) void k_xcast(const void* __restrict__ x,
                                               u16* __restrict__ xb,
                                               const int* __restrict__ flag) {
    int isf32 = *flag;
    int n = blockIdx.x * 256 + threadIdx.x;
    if (n < NNODES)
        xb[n] = isf32 ? f2b(((const float*)x)[n]) : ((const u16*)x)[n];
}

// ------- per-chunk bucket histogram -> cnt[chunk][bucket] (u16) ---------

__global__ __launch_bounds__(512) void k_hist(const int* __restrict__ dst,
                                              u16* __restrict__ cnt) {
    __shared__ u32 h[NBUCK];
    int t = threadIdx.x;
    int chunk = blockIdx.x;
    int c0 = chunk * PCHUNK;
    for (int b = t; b < NBUCK; b += 512) h[b] = 0;
    __syncthreads();
#pragma unroll
    for (int k = 0; k < 8; k++) {
        int e = c0 + k * 512 + t;
        if (e < NEDGES) atomicAdd(&h[((u32)dst[e]) >> BSH], 1u);
    }
    __syncthreads();
    size_t row = (size_t)chunk * NBUCK;
    for (int b = t; b < NBUCK; b += 512) cnt[row + b] = (u16)h[b];
}

// -- column scan over chunks (per segment): off[chunk][b], st[seg][b] ----

__global__ __launch_bounds__(64) void k_mscanA(const u16* __restrict__ cnt,
                                               u16* __restrict__ offm,
                                               u16* __restrict__ st) {
    int seg  = blockIdx.x / NTILE;
    int tile = blockIdx.x % NTILE;
    int b = tile * 64 + threadIdx.x;
    if (b >= NBUCK) return;
    int cS = seg * SEGC;
    int cE = cS + SEGC; if (cE > PBLK) cE = PBLK;
    u32 run = 0;
#pragma unroll 4
    for (int c = cS; c < cE; c++) {
        size_t idx = (size_t)c * NBUCK + b;
        u32 v = (u32)cnt[idx];
        offm[idx] = (u16)run;
        run += v;
    }
    st[(size_t)seg * NBUCK + b] = (u16)run;
}

// -- combine: bucket totals -> bstart[], per-seg bases (bstart folded) ---

__global__ __launch_bounds__(256) void k_mscanB(const u16* __restrict__ st,
                                                int* __restrict__ bstart,
                                                u32* __restrict__ segb) {
    __shared__ u32 sd[256];
    __shared__ u32 carry;
    int t = threadIdx.x;
    if (t == 0) carry = 0;
    __syncthreads();
    for (int c0 = 0; c0 < NBUCK; c0 += 256) {
        int b = c0 + t;
        u32 tot = 0;
        if (b < NBUCK)
#pragma unroll
            for (int s = 0; s < NSEG; s++) tot += (u32)st[(size_t)s * NBUCK + b];
        sd[t] = tot; __syncthreads();
        for (int o = 1; o < 256; o <<= 1) {
            u32 a = (t >= o) ? sd[t - o] : 0;
            __syncthreads();
            sd[t] += a;
            __syncthreads();
        }
        u32 excl = carry + sd[t] - tot;
        if (b < NBUCK) {
            bstart[b] = (int)excl;
            u32 r = excl;
#pragma unroll
            for (int s = 0; s < NSEG; s++) {
                segb[(size_t)s * NBUCK + b] = r;
                r += (u32)st[(size_t)s * NBUCK + b];
            }
        }
        __syncthreads();
        if (t == 255) carry += sd[255];
        __syncthreads();
    }
    if (t == 0) bstart[NBUCK] = NEDGES;
}

// ---- partition: precomputed offsets, LDS counting sort, ordered flush ----
// LDS: cur 11.7K + gbA 11.7K + rec 32K + bid 8K = 63.4KB (static, fits).
// Zero global atomics. Scan temp overlays rec (dead until edge pass).

__global__ __launch_bounds__(512) void k_part(const int* __restrict__ src,
                                              const int* __restrict__ dst,
                                              const void* __restrict__ attr,
                                              const u16* __restrict__ cnt,
                                              const u16* __restrict__ offm,
                                              const u32* __restrict__ segb,
                                              uint2* __restrict__ perm,
                                              const int* __restrict__ flag) {
    __shared__ u32   cur[NBUCK];    // cnt -> local excl start -> cursor
    __shared__ u32   gbA[NBUCK];    // global base minus local start
    __shared__ uint2 rec[PCHUNK];   // bucket-grouped records
    __shared__ u16   bid[PCHUNK];   // per-slot bucket id
    __shared__ u32   carryS;
    u32* sd = reinterpret_cast<u32*>(rec);   // 2KB scan temp overlay
    int isf32 = *flag;
    int t = threadIdx.x;
    int chunk = blockIdx.x;
    int seg = chunk / SEGC;
    int c0 = chunk * PCHUNK;
    int chunkN = NEDGES - c0; if (chunkN > PCHUNK) chunkN = PCHUNK;
    size_t row = (size_t)chunk * NBUCK;

    // load this chunk's per-bucket counts
    for (int b = t; b < NBUCK; b += 512) cur[b] = (u32)cnt[row + b];
    if (t == 0) carryS = 0;
    __syncthreads();

    // local exclusive scan (in place), temp in rec-overlay
    for (int b0 = 0; b0 < NBUCK; b0 += 512) {
        int b = b0 + t;
        u32 v = (b < NBUCK) ? cur[b] : 0;
        sd[t] = v; __syncthreads();
        for (int o = 1; o < 512; o <<= 1) {
            u32 a = (t >= o) ? sd[t - o] : 0;
            __syncthreads();
            sd[t] += a;
            __syncthreads();
        }
        u32 excl = carryS + sd[t] - v;
        if (b < NBUCK) cur[b] = excl;
        __syncthreads();
        if (t == 511) carryS += sd[511];
        __syncthreads();
    }

    // global base minus local start (all precomputed, coalesced reads)
    for (int b = t; b < NBUCK; b += 512)
        gbA[b] = segb[(size_t)seg * NBUCK + b] + (u32)offm[row + b] - cur[b];
    __syncthreads();

    // fused edge pass: read, pack, scatter into LDS by bucket
#pragma unroll
    for (int k = 0; k < 8; k++) {
        int e = c0 + k * 512 + t;
        if (e < NEDGES) {
            u32 d = (u32)dst[e];
            u32 s = (u32)src[e];
            u32 fb = d >> BSH;
            u32 ap;
            if (isf32) {
                float2 a = ((const float2*)attr)[e];
                ap = (u32)f2b(a.x) | ((u32)f2b(a.y) << 16);
            } else {
                ap = ((const u32*)attr)[e];
            }
            int slot = (int)atomicAdd(&cur[fb], 1u);
            uint2 r; r.x = s | ((d & BMASK) << 21); r.y = ap;
            rec[slot] = r;
            bid[slot] = (u16)fb;
        }
    }
    __syncthreads();

    // ordered flush: ascending slot = ascending global address per bucket
#pragma unroll
    for (int j = 0; j < 8; j++) {
        int s = j * 512 + t;
        if (s < chunkN) {
            u32 fb = (u32)bid[s];
            perm[gbA[fb] + s] = rec[s];
        }
    }
}

// ---- k_srt: in-place per-bucket counting sort by src slice (src>>15) ----
// Keeps the 3MB hB table L2-resident in the eagg kernels (proven R10) and
// gives ~12% intra-wave hA line sharing.

__global__ __launch_bounds__(256) void k_srt(const int* __restrict__ bstart,
                                             uint2* __restrict__ perm) {
    __shared__ int h[NSLICE];
    int t = threadIdx.x;
    int b = blockIdx.x;
    int r0 = bstart[b], r1 = bstart[b + 1];
    int len = r1 - r0;
    if (len <= 0) return;                 // uniform branch
    if (len > SRTR * 256) return;         // safety: leave bucket unsorted
    if (t < NSLICE) h[t] = 0;
    __syncthreads();

    uint2 r[SRTR];
#pragma unroll
    for (int k = 0; k < SRTR; k++) {
        int i = r0 + k * 256 + t;
        if (i < r1) {
            r[k] = perm[i];
            atomicAdd(&h[(r[k].x & SRCMASK) >> 15], 1);
        } else {
            r[k].x = 0xFFFFFFFFu;         // rec.x < 2^30 => safe sentinel
        }
    }
    __syncthreads();                      // all reads done before any write

    if (t == 0) {
        int s = 0;
        for (int k = 0; k < NSLICE; k++) { int c = h[k]; h[k] = s; s += c; }
    }
    __syncthreads();

#pragma unroll
    for (int k = 0; k < SRTR; k++) {
        if (r[k].x != 0xFFFFFFFFu) {
            int slot = atomicAdd(&h[(r[k].x & SRCMASK) >> 15], 1);
            perm[r0 + slot] = r[k];       // scatter within 36KB window: L2-merged
        }
    }
}

// ---- per-edge update helpers (always inlined; acc stays LDS-addrspace) ----

static __device__ __forceinline__ void upd1(uint2 rec, float xs,
                                            const float* sWx, const float* sbx,
                                            const float* sWe, const float* sbe,
                                            int* acc) {
    int   l  = (int)((rec.x >> 21) & BMASK);
    float a0 = b2f(rec.y & 0xffffu);
    float a1 = b2f(rec.y >> 16);
    int* ap = &acc[l * 9];
#pragma unroll
    for (int j = 0; j < 9; j++) {
        float e  = fmaf(a0, sWe[2 * j], fmaf(a1, sWe[2 * j + 1], sbe[j]));
        float hh = fmaf(xs, sWx[j], sbx[j]);
        atomicAdd(&ap[j], fx(hh * e));     // native ds_add_u32
    }
}

static __device__ __forceinline__ void upd2(uint2 rec, uint4 qa, u32 qb,
                                            const float* sWe, const float* sbe,
                                            int* acc) {
    int   l  = (int)((rec.x >> 21) & BMASK);
    float a0 = b2f(rec.y & 0xffffu);
    float a1 = b2f(rec.y >> 16);
    float h[9];
    h[0] = b2f(qa.x & 0xffffu); h[1] = b2f(qa.x >> 16);
    h[2] = b2f(qa.y & 0xffffu); h[3] = b2f(qa.y >> 16);
    h[4] = b2f(qa.z & 0xffffu); h[5] = b2f(qa.z >> 16);
    h[6] = b2f(qa.w & 0xffffu); h[7] = b2f(qa.w >> 16);
    h[8] = b2f(qb & 0xffffu);
    int* ap = &acc[l * 9];
#pragma unroll
    for (int j = 0; j < 9; j++) {
        float e = fmaf(a0, sWe[2 * j], fmaf(a1, sWe[2 * j + 1], sbe[j]));
        atomicAdd(&ap[j], fx(h[j] * e));
    }
}

// ---- layer 1 (edge-centric): gather bf16 x (L2-resident), fx LDS acc ----

__global__ __launch_bounds__(256) void k_eagg1(
        const int* __restrict__ bstart, const uint2* __restrict__ perm,
        const u16* __restrict__ xb,
        const void* Wx, const void* bx, const void* We, const void* be,
        const void* Wo, const void* bo, const void* Wxn, const void* bxn,
        uint4* __restrict__ hA, u16* __restrict__ hB,
        const int* __restrict__ flag) {
    __shared__ int acc[BSZ * 9];
    __shared__ float sWx[9], sbx[9], sWe[18], sbe[9], sWo[81], sbo[9], sWxn[81], sbxn[9];
    int isf32 = *flag;
    int t = threadIdx.x;
    if (t < 9)  sWx[t]  = ldw(Wx,  t, isf32);
    if (t < 9)  sbx[t]  = ldw(bx,  t, isf32);
    if (t < 18) sWe[t]  = ldw(We,  t, isf32);
    if (t < 9)  sbe[t]  = ldw(be,  t, isf32);
    if (t < 81) sWo[t]  = ldw(Wo,  t, isf32);
    if (t < 9)  sbo[t]  = ldw(bo,  t, isf32);
    if (t < 81) sWxn[t] = ldw(Wxn, t, isf32);
    if (t < 9)  sbxn[t] = ldw(bxn, t, isf32);
    for (int i = t; i < BSZ * 9; i += 256) acc[i] = 0;
    __syncthreads();

    int b = blockIdx.x;
    int r0 = bstart[b], r1 = bstart[b + 1];
    int i = r0 + t;
    // 4-deep software pipeline: all loads issued before any compute
    for (; i + 768 < r1; i += 1024) {
        uint2 e0 = perm[i], e1 = perm[i + 256], e2 = perm[i + 512], e3 = perm[i + 768];
        float x0 = b2f((u32)xb[e0.x & SRCMASK]);
        float x1 = b2f((u32)xb[e1.x & SRCMASK]);
        float x2 = b2f((u32)xb[e2.x & SRCMASK]);
        float x3 = b2f((u32)xb[e3.x & SRCMASK]);
        upd1(e0, x0, sWx, sbx, sWe, sbe, acc);
        upd1(e1, x1, sWx, sbx, sWe, sbe, acc);
        upd1(e2, x2, sWx, sbx, sWe, sbe, acc);
        upd1(e3, x3, sWx, sbx, sWe, sbe, acc);
    }
    for (; i < r1; i += 256) {
        uint2 e0 = perm[i];
        float x0 = b2f((u32)xb[e0.x & SRCMASK]);
        upd1(e0, x0, sWx, sbx, sWe, sbe, acc);
    }
    __syncthreads();

    for (int l = t; l < BSZ; l += 256) {
        int n = b * BSZ + l;
        if (n >= NNODES) break;
        float av[9];
#pragma unroll
        for (int j = 0; j < 9; j++) av[j] = (float)acc[l * 9 + j] * FXINV;
        float o[9];
#pragma unroll
        for (int k = 0; k < 9; k++) {
            float v = sbo[k];
#pragma unroll
            for (int j = 0; j < 9; j++) v = fmaf(av[j], sWo[k * 9 + j], v);
            o[k] = fmaxf(v, 0.f);
        }
        u16 hv[9];
#pragma unroll
        for (int j = 0; j < 9; j++) {
            float v = sbxn[j];
#pragma unroll
            for (int k = 0; k < 9; k++) v = fmaf(o[k], sWxn[j * 9 + k], v);
            hv[j] = f2b(v);
        }
        uint4 q;
        q.x = (u32)hv[0] | ((u32)hv[1] << 16);
        q.y = (u32)hv[2] | ((u32)hv[3] << 16);
        q.z = (u32)hv[4] | ((u32)hv[5] << 16);
        q.w = (u32)hv[6] | ((u32)hv[7] << 16);
        hA[n] = q;
        hB[n] = hv[8];
    }
}

// ---- layers 2/3 (edge-centric): gather 16B+2B split tables, fx LDS acc ----

template <int OUTF, bool FUSE_NEXT>
__global__ __launch_bounds__(256) void k_eagg(
        const int* __restrict__ bstart, const uint2* __restrict__ perm,
        const uint4* __restrict__ hA, const u16* __restrict__ hB,
        const void* We, const void* be, const void* Wo, const void* bo,
        const void* Wxn, const void* bxn,
        uint4* __restrict__ oA, u16* __restrict__ oB,
        const int* __restrict__ flag) {
    __shared__ int acc[BSZ * 9];
    __shared__ float sWe[18], sbe[9], sWo[OUTF * 9], sbo[OUTF];
    __shared__ float sWxn[FUSE_NEXT ? 81 : 1], sbxn[FUSE_NEXT ? 9 : 1];
    int isf32 = *flag;
    int t = threadIdx.x;
    if (t < 18)       sWe[t] = ldw(We, t, isf32);
    if (t < 9)        sbe[t] = ldw(be, t, isf32);
    if (t < OUTF * 9) sWo[t] = ldw(Wo, t, isf32);
    if (t < OUTF)     sbo[t] = ldw(bo, t, isf32);
    if constexpr (FUSE_NEXT) {
        if (t < 81) sWxn[t] = ldw(Wxn, t, isf32);
        if (t < 9)  sbxn[t] = ldw(bxn, t, isf32);
    }
    for (int i = t; i < BSZ * 9; i += 256) acc[i] = 0;
    __syncthreads();

    int b = blockIdx.x;
    int r0 = bstart[b], r1 = bstart[b + 1];
    int i = r0 + t;
    // 4-deep software pipeline: 4 perm loads + 4 gathers in flight
    for (; i + 768 < r1; i += 1024) {
        uint2 e0 = perm[i], e1 = perm[i + 256], e2 = perm[i + 512], e3 = perm[i + 768];
        int s0 = (int)(e0.x & SRCMASK), s1 = (int)(e1.x & SRCMASK);
        int s2 = (int)(e2.x & SRCMASK), s3 = (int)(e3.x & SRCMASK);
        uint4 qa0 = hA[s0], qa1 = hA[s1], qa2 = hA[s2], qa3 = hA[s3];
        u32   qb0 = (u32)hB[s0], qb1 = (u32)hB[s1], qb2 = (u32)hB[s2], qb3 = (u32)hB[s3];
        upd2(e0, qa0, qb0, sWe, sbe, acc);
        upd2(e1, qa1, qb1, sWe, sbe, acc);
        upd2(e2, qa2, qb2, sWe, sbe, acc);
        upd2(e3, qa3, qb3, sWe, sbe, acc);
    }
    for (; i < r1; i += 256) {
        uint2 e0 = perm[i];
        int s0 = (int)(e0.x & SRCMASK);
        uint4 qa0 = hA[s0];
        u32   qb0 = (u32)hB[s0];
        upd2(e0, qa0, qb0, sWe, sbe, acc);
    }
    __syncthreads();

    for (int l = t; l < BSZ; l += 256) {
        int n = b * BSZ + l;
        if (n >= NNODES) break;
        float av[9];
#pragma unroll
        for (int j = 0; j < 9; j++) av[j] = (float)acc[l * 9 + j] * FXINV;
        float o[OUTF];
#pragma unroll
        for (int k = 0; k < OUTF; k++) {
            float v = sbo[k];
#pragma unroll
            for (int j = 0; j < 9; j++) v = fmaf(av[j], sWo[k * 9 + j], v);
            o[k] = fmaxf(v, 0.f);
        }
        if constexpr (FUSE_NEXT) {
            u16 hv[9];
#pragma unroll
            for (int j = 0; j < 9; j++) {
                float v = sbxn[j];
#pragma unroll
                for (int k = 0; k < OUTF; k++) v = fmaf(o[k], sWxn[j * 9 + k], v);
                hv[j] = f2b(v);
            }
            uint4 q;
            q.x = (u32)hv[0] | ((u32)hv[1] << 16);
            q.y = (u32)hv[2] | ((u32)hv[3] << 16);
            q.z = (u32)hv[4] | ((u32)hv[5] << 16);
            q.w = (u32)hv[6] | ((u32)hv[7] << 16);
            oA[n] = q;
            oB[n] = hv[8];
        } else {
            uint2 q;
            q.x = (u32)f2b(o[0]) | ((u32)f2b(o[1]) << 16);
            q.y = (u32)f2b(o[2]) | ((u32)f2b(o[3]) << 16);
            ((uint2*)oA)[n] = q;   // f table: 8B/node
        }
    }
}

// ---------------- head MLP + log_softmax ----------------

__global__ __launch_bounds__(256) void k_head(
        const u16* __restrict__ f,
        const void* W1, const void* b1, const void* W2, const void* b2,
        void* __restrict__ out, const int* __restrict__ flag) {
    __shared__ float sW1[192], sb1[8], sW2[32], sb2[4];
    int isf32 = *flag;
    int t = threadIdx.x;
    if (t < 192) sW1[t] = ldw(W1, t, isf32);
    if (t < 8)   sb1[t] = ldw(b1, t, isf32);
    if (t < 32)  sW2[t] = ldw(W2, t, isf32);
    if (t < 4)   sb2[t] = ldw(b2, t, isf32);
    __syncthreads();

    int tr = blockIdx.x * 256 + t;
    if (tr >= NTRACK) return;

    const uint4* fp = (const uint4*)(f + (size_t)tr * 24);
    uint4 A = fp[0], B = fp[1], C = fp[2];
    u32 w[12] = {A.x, A.y, A.z, A.w, B.x, B.y, B.z, B.w, C.x, C.y, C.z, C.w};
    float in[24];
#pragma unroll
    for (int i = 0; i < 12; i++) {
        in[2 * i]     = b2f(w[i] & 0xffffu);
        in[2 * i + 1] = b2f(w[i] >> 16);
    }

    float z1[8];
#pragma unroll
    for (int o = 0; o < 8; o++) {
        float v = sb1[o];
#pragma unroll
        for (int i = 0; i < 24; i++) v = fmaf(in[i], sW1[o * 24 + i], v);
        z1[o] = fmaxf(v, 0.f);
    }
    float z2[4];
#pragma unroll
    for (int c = 0; c < 4; c++) {
        float v = sb2[c];
#pragma unroll
        for (int o = 0; o < 8; o++) v = fmaf(z1[o], sW2[c * 8 + o], v);
        z2[c] = v;
    }
    float m = fmaxf(fmaxf(z2[0], z2[1]), fmaxf(z2[2], z2[3]));
    float s = 0.f;
#pragma unroll
    for (int c = 0; c < 4; c++) s += expf(z2[c] - m);
    float l = logf(s) + m;

    if (isf32) {
        float4 q; q.x = z2[0] - l; q.y = z2[1] - l; q.z = z2[2] - l; q.w = z2[3] - l;
        ((float4*)((float*)out + (size_t)tr * 4))[0] = q;
    } else {
        uint2 q;
        q.x = (u32)f2b(z2[0] - l) | ((u32)f2b(z2[1] - l) << 16);
        q.y = (u32)f2b(z2[2] - l) | ((u32)f2b(z2[3] - l) << 16);
        ((uint2*)((u16*)out + (size_t)tr * 4))[0] = q;
    }
}

// ---------------- host ----------------

extern "C" void kernel_launch(void* const* d_in, const int* in_sizes, int n_in,
                              void* d_out, int out_size, void* d_ws, size_t ws_size,
                              hipStream_t stream) {
    const void* X    = d_in[0];
    const int* eidx  = (const int*)d_in[1];
    const void* eattr= d_in[2];
    const void *WX1 = d_in[3],  *BX1 = d_in[4];
    const void *WE1 = d_in[5],  *BE1 = d_in[6];
    const void *WO1 = d_in[7],  *BO1 = d_in[8];
    const void *WX2 = d_in[9],  *BX2 = d_in[10];
    const void *WE2 = d_in[11], *BE2 = d_in[12];
    const void *WO2 = d_in[13], *BO2 = d_in[14];
    const void *WX3 = d_in[15], *BX3 = d_in[16];
    const void *WE3 = d_in[17], *BE3 = d_in[18];
    const void *WO3 = d_in[19], *BO3 = d_in[20];
    const void *W1  = d_in[21], *B1  = d_in[22];
    const void *W2  = d_in[23], *B2  = d_in[24];

    const int* src = eidx;
    const int* dst = eidx + NEDGES;

    // workspace layout (~189 MB)
    char* w = (char*)d_ws;
    size_t off = 0;
    auto take = [&](size_t bytes) -> void* {
        void* p = w + off;
        off += (bytes + 255) & ~(size_t)255;
        return p;
    };
    int*   flag   = (int*)take(256);
    int*   bstart = (int*)take((size_t)(NBUCK + 1) * 4);
    u16*   cnt    = (u16*)take((size_t)PBLK * NBUCK * 2);   // 17.2 MB
    u16*   offm   = (u16*)take((size_t)PBLK * NBUCK * 2);   // 17.2 MB
    u16*   st     = (u16*)take((size_t)NSEG * NBUCK * 2);   // 188 KB
    u32*   segb   = (u32*)take((size_t)NSEG * NBUCK * 4);   // 375 KB
    u16*   xb     = (u16*)take((size_t)NNODES * 2);         // 3 MB bf16 x
    uint2* perm   = (uint2*)take((size_t)NEDGES * 8);       // 96 MB exact
    uint4* hA2    = (uint4*)take((size_t)NNODES * 16);      // 24 MB
    u16*   hB2    = (u16*)take((size_t)NNODES * 2);         // 3 MB
    uint4* hA3    = (uint4*)take((size_t)NNODES * 16);      // 24 MB
    u16*   hB3    = (u16*)take((size_t)NNODES * 2);         // 3 MB
    u16*   f      = (u16*)hA2;  // layer-3 output (12 MB) reuses hA2 (dead by then)
    (void)ws_size; (void)n_in; (void)in_sizes; (void)out_size;

    const int NB = (NNODES + 255) / 256;
    const int TB = (NTRACK + 255) / 256;

    k_detect <<<1,    64,  0, stream>>>((const u16*)BX1, (const u16*)BE1, (const u16*)BO1,
                                        (const u16*)BX2, (const u16*)BE2, (const u16*)B1, flag);
    k_xcast  <<<NB,   256, 0, stream>>>(X, xb, flag);
    k_hist   <<<PBLK, 512, 0, stream>>>(dst, cnt);
    k_mscanA <<<NSEG * NTILE, 64, 0, stream>>>(cnt, offm, st);
    k_mscanB <<<1,    256, 0, stream>>>(st, bstart, segb);
    k_part   <<<PBLK, 512, 0, stream>>>(src, dst, eattr, cnt, offm, segb, perm, flag);
    k_srt    <<<NBUCK,256, 0, stream>>>(bstart, perm);

    k_eagg1        <<<NBUCK, 256, 0, stream>>>(bstart, perm, xb,
                                               WX1, BX1, WE1, BE1, WO1, BO1, WX2, BX2,
                                               hA2, hB2, flag);
    k_eagg<9,true> <<<NBUCK, 256, 0, stream>>>(bstart, perm, hA2, hB2,
                                               WE2, BE2, WO2, BO2, WX3, BX3,
                                               hA3, hB3, flag);
    k_eagg<4,false><<<NBUCK, 256, 0, stream>>>(bstart, perm, hA3, hB3,
                                               WE3, BE3, WO3, BO3, WO3, BO3,
                                               (uint4*)f, (u16*)f, flag);
    k_head         <<<TB,    256, 0, stream>>>(f, W1, B1, W2, B2, d_out, flag);
}

// Round 5
// 1015.617 us; speedup vs baseline: 1.0711x; 1.0711x over previous
//
#include <hip/hip_runtime.h>
#include <hip/hip_bf16.h>

// trackletGNN: 3x edge-conv + MLP head.
// R12: exact-resident cohort sweep for the gather kernels.
// R11 post-mortem: x4 MLP pipeline REGRESSED (224->247us, FETCH 780->885MB,
// rate pinned at 3.7TB/s). With R8 (occ x2 -> +12%) this triple-confirms:
// eagg is SATURATED on the L2-miss 64B-sector fill path (~3.6-3.9 TB/s),
// not latency-bound. Also the 4 in-flight gathers spanned 4 src-slices,
// diluting intra-wave line sharing (FETCH +13%). Lever = bytes, not MLP.
// R9's sliding-window failed because grid 2930 > residency 2048: 882
// latecomer blocks (43%) sweep from slice 0 against the cohort at slice 40,
// thrashing L2. R12: eagg l2/l3 grid = 1465 blocks (ALL resident at t=0),
// each processes bucket pair (2b, 2b+1) sequentially with the R10 simple
// loop. Equal work (8192 edges +-1.6%) + simultaneous start => blocks sweep
// src-slices in loose lockstep; live table window ~0.5-1.5MB fits per-XCD
// L2. Expected: FETCH 885 -> ~350-500MB, dur 247 -> ~120-160us each.
// eagg1 untouched (3MB xb already L2-resident). Bit-identical output.

#define NNODES 1500000
#define NEDGES 12000000
#define NTRACK 250000
#define BSH    9           // log2(bucket size)
#define BSZ    512         // nodes per agg bucket
#define BMASK  511u
#define NBUCK  2930        // ceil(NNODES/512)
#define EGRID  1465        // eagg l2/l3 blocks (bucket pairs, all-resident)
#define PCHUNK 4096        // edges per k_part block (LDS-sorted)
#define PBLK   2930        // ceil(NEDGES/PCHUNK)
#define NSEG   32          // chunk segments for the column scan
#define SEGC   92          // chunks per segment (32*92 >= 2930)
#define NTILE  46          // bucket tiles of 64 ((2930+63)/64)
#define SRCMASK 0x1FFFFFu  // 21 bits
#define NSLICE 48          // src slices (src>>15, 512KB of hA each)
#define SRTR   20          // k_srt records/thread (covers runs to 5120)
#define FXSCALE 16777216.f // 2^24
#define FXINV   (1.f / 16777216.f)

typedef unsigned int   u32;
typedef unsigned short u16;

static __device__ __forceinline__ float b2f(u32 v) {
    union { float f; u32 u; } x; x.u = v << 16; return x.f;
}
static __device__ __forceinline__ u16 f2b(float f) {
    __hip_bfloat16 h = __float2bfloat16(f);
    return *reinterpret_cast<u16*>(&h);
}
static __device__ __forceinline__ float ldw(const void* p, int i, int isf32) {
    return isf32 ? ((const float*)p)[i] : b2f((u32)((const u16*)p)[i]);
}
static __device__ __forceinline__ int fx(float f) {
    return (int)rintf(f * FXSCALE);
}

// ---------------- dtype probe ----------------

__global__ void k_detect(const u16* a, const u16* b, const u16* c,
                         const u16* d, const u16* e, const u16* f,
                         int* flag) {
    if (blockIdx.x == 0 && threadIdx.x == 0) {
        int isf32 = 0;
        const u16* ps[6] = {a, b, c, d, e, f};
        const int  ns[6] = {9, 9, 9, 9, 9, 8};
        for (int k = 0; k < 6; k++)
            for (int i = 0; i < ns[k]; i++) {
                float v = b2f((u32)ps[k][i]);
                if (!(fabsf(v) < 1.0e3f)) isf32 = 1;   // catches NaN/Inf too
            }
        *flag = isf32;
    }
}

// ------------- x -> bf16 table (3 MB, fits per-XCD L2 for layer 1) -------

__global__ __launch_bounds__(256) void k_xcast(const void* __restrict__ x,
                                               u16* __restrict__ xb,
                                               const int* __restrict__ flag) {
    int isf32 = *flag;
    int n = blockIdx.x * 256 + threadIdx.x;
    if (n < NNODES)
        xb[n] = isf32 ? f2b(((const float*)x)[n]) : ((const u16*)x)[n];
}

// ------- per-chunk bucket histogram -> cnt[chunk][bucket] (u16) ---------

__global__ __launch_bounds__(512) void k_hist(const int* __restrict__ dst,
                                              u16* __restrict__ cnt) {
    __shared__ u32 h[NBUCK];
    int t = threadIdx.x;
    int chunk = blockIdx.x;
    int c0 = chunk * PCHUNK;
    for (int b = t; b < NBUCK; b += 512) h[b] = 0;
    __syncthreads();
#pragma unroll
    for (int k = 0; k < 8; k++) {
        int e = c0 + k * 512 + t;
        if (e < NEDGES) atomicAdd(&h[((u32)dst[e]) >> BSH], 1u);
    }
    __syncthreads();
    size_t row = (size_t)chunk * NBUCK;
    for (int b = t; b < NBUCK; b += 512) cnt[row + b] = (u16)h[b];
}

// -- column scan over chunks (per segment): off[chunk][b], st[seg][b] ----

__global__ __launch_bounds__(64) void k_mscanA(const u16* __restrict__ cnt,
                                               u16* __restrict__ offm,
                                               u16* __restrict__ st) {
    int seg  = blockIdx.x / NTILE;
    int tile = blockIdx.x % NTILE;
    int b = tile * 64 + threadIdx.x;
    if (b >= NBUCK) return;
    int cS = seg * SEGC;
    int cE = cS + SEGC; if (cE > PBLK) cE = PBLK;
    u32 run = 0;
#pragma unroll 4
    for (int c = cS; c < cE; c++) {
        size_t idx = (size_t)c * NBUCK + b;
        u32 v = (u32)cnt[idx];
        offm[idx] = (u16)run;
        run += v;
    }
    st[(size_t)seg * NBUCK + b] = (u16)run;
}

// -- combine: bucket totals -> bstart[], per-seg bases (bstart folded) ---

__global__ __launch_bounds__(256) void k_mscanB(const u16* __restrict__ st,
                                                int* __restrict__ bstart,
                                                u32* __restrict__ segb) {
    __shared__ u32 sd[256];
    __shared__ u32 carry;
    int t = threadIdx.x;
    if (t == 0) carry = 0;
    __syncthreads();
    for (int c0 = 0; c0 < NBUCK; c0 += 256) {
        int b = c0 + t;
        u32 tot = 0;
        if (b < NBUCK)
#pragma unroll
            for (int s = 0; s < NSEG; s++) tot += (u32)st[(size_t)s * NBUCK + b];
        sd[t] = tot; __syncthreads();
        for (int o = 1; o < 256; o <<= 1) {
            u32 a = (t >= o) ? sd[t - o] : 0;
            __syncthreads();
            sd[t] += a;
            __syncthreads();
        }
        u32 excl = carry + sd[t] - tot;
        if (b < NBUCK) {
            bstart[b] = (int)excl;
            u32 r = excl;
#pragma unroll
            for (int s = 0; s < NSEG; s++) {
                segb[(size_t)s * NBUCK + b] = r;
                r += (u32)st[(size_t)s * NBUCK + b];
            }
        }
        __syncthreads();
        if (t == 255) carry += sd[255];
        __syncthreads();
    }
    if (t == 0) bstart[NBUCK] = NEDGES;
}

// ---- partition: precomputed offsets, LDS counting sort, ordered flush ----
// LDS: cur 11.7K + gbA 11.7K + rec 32K + bid 8K = 63.4KB (static, fits).
// Zero global atomics. Scan temp overlays rec (dead until edge pass).

__global__ __launch_bounds__(512) void k_part(const int* __restrict__ src,
                                              const int* __restrict__ dst,
                                              const void* __restrict__ attr,
                                              const u16* __restrict__ cnt,
                                              const u16* __restrict__ offm,
                                              const u32* __restrict__ segb,
                                              uint2* __restrict__ perm,
                                              const int* __restrict__ flag) {
    __shared__ u32   cur[NBUCK];    // cnt -> local excl start -> cursor
    __shared__ u32   gbA[NBUCK];    // global base minus local start
    __shared__ uint2 rec[PCHUNK];   // bucket-grouped records
    __shared__ u16   bid[PCHUNK];   // per-slot bucket id
    __shared__ u32   carryS;
    u32* sd = reinterpret_cast<u32*>(rec);   // 2KB scan temp overlay
    int isf32 = *flag;
    int t = threadIdx.x;
    int chunk = blockIdx.x;
    int seg = chunk / SEGC;
    int c0 = chunk * PCHUNK;
    int chunkN = NEDGES - c0; if (chunkN > PCHUNK) chunkN = PCHUNK;
    size_t row = (size_t)chunk * NBUCK;

    // load this chunk's per-bucket counts
    for (int b = t; b < NBUCK; b += 512) cur[b] = (u32)cnt[row + b];
    if (t == 0) carryS = 0;
    __syncthreads();

    // local exclusive scan (in place), temp in rec-overlay
    for (int b0 = 0; b0 < NBUCK; b0 += 512) {
        int b = b0 + t;
        u32 v = (b < NBUCK) ? cur[b] : 0;
        sd[t] = v; __syncthreads();
        for (int o = 1; o < 512; o <<= 1) {
            u32 a = (t >= o) ? sd[t - o] : 0;
            __syncthreads();
            sd[t] += a;
            __syncthreads();
        }
        u32 excl = carryS + sd[t] - v;
        if (b < NBUCK) cur[b] = excl;
        __syncthreads();
        if (t == 511) carryS += sd[511];
        __syncthreads();
    }

    // global base minus local start (all precomputed, coalesced reads)
    for (int b = t; b < NBUCK; b += 512)
        gbA[b] = segb[(size_t)seg * NBUCK + b] + (u32)offm[row + b] - cur[b];
    __syncthreads();

    // fused edge pass: read, pack, scatter into LDS by bucket
#pragma unroll
    for (int k = 0; k < 8; k++) {
        int e = c0 + k * 512 + t;
        if (e < NEDGES) {
            u32 d = (u32)dst[e];
            u32 s = (u32)src[e];
            u32 fb = d >> BSH;
            u32 ap;
            if (isf32) {
                float2 a = ((const float2*)attr)[e];
                ap = (u32)f2b(a.x) | ((u32)f2b(a.y) << 16);
            } else {
                ap = ((const u32*)attr)[e];
            }
            int slot = (int)atomicAdd(&cur[fb], 1u);
            uint2 r; r.x = s | ((d & BMASK) << 21); r.y = ap;
            rec[slot] = r;
            bid[slot] = (u16)fb;
        }
    }
    __syncthreads();

    // ordered flush: ascending slot = ascending global address per bucket
#pragma unroll
    for (int j = 0; j < 8; j++) {
        int s = j * 512 + t;
        if (s < chunkN) {
            u32 fb = (u32)bid[s];
            perm[gbA[fb] + s] = rec[s];
        }
    }
}

// ---- k_srt: in-place per-bucket counting sort by src slice (src>>15) ----
// Gives the eagg sweep its monotone gather order (cohort L2 window) and
// keeps the 3MB hB table L2-resident.

__global__ __launch_bounds__(256) void k_srt(const int* __restrict__ bstart,
                                             uint2* __restrict__ perm) {
    __shared__ int h[NSLICE];
    int t = threadIdx.x;
    int b = blockIdx.x;
    int r0 = bstart[b], r1 = bstart[b + 1];
    int len = r1 - r0;
    if (len <= 0) return;                 // uniform branch
    if (len > SRTR * 256) return;         // safety: leave bucket unsorted
    if (t < NSLICE) h[t] = 0;
    __syncthreads();

    uint2 r[SRTR];
#pragma unroll
    for (int k = 0; k < SRTR; k++) {
        int i = r0 + k * 256 + t;
        if (i < r1) {
            r[k] = perm[i];
            atomicAdd(&h[(r[k].x & SRCMASK) >> 15], 1);
        } else {
            r[k].x = 0xFFFFFFFFu;         // rec.x < 2^30 => safe sentinel
        }
    }
    __syncthreads();                      // all reads done before any write

    if (t == 0) {
        int s = 0;
        for (int k = 0; k < NSLICE; k++) { int c = h[k]; h[k] = s; s += c; }
    }
    __syncthreads();

#pragma unroll
    for (int k = 0; k < SRTR; k++) {
        if (r[k].x != 0xFFFFFFFFu) {
            int slot = atomicAdd(&h[(r[k].x & SRCMASK) >> 15], 1);
            perm[r0 + slot] = r[k];       // scatter within 36KB window: L2-merged
        }
    }
}

// ---- layer 1 (edge-centric): gather bf16 x (L2-resident), fx LDS acc ----

__global__ __launch_bounds__(256) void k_eagg1(
        const int* __restrict__ bstart, const uint2* __restrict__ perm,
        const u16* __restrict__ xb,
        const void* Wx, const void* bx, const void* We, const void* be,
        const void* Wo, const void* bo, const void* Wxn, const void* bxn,
        uint4* __restrict__ hA, u16* __restrict__ hB,
        const int* __restrict__ flag) {
    __shared__ int acc[BSZ * 9];
    __shared__ float sWx[9], sbx[9], sWe[18], sbe[9], sWo[81], sbo[9], sWxn[81], sbxn[9];
    int isf32 = *flag;
    int t = threadIdx.x;
    if (t < 9)  sWx[t]  = ldw(Wx,  t, isf32);
    if (t < 9)  sbx[t]  = ldw(bx,  t, isf32);
    if (t < 18) sWe[t]  = ldw(We,  t, isf32);
    if (t < 9)  sbe[t]  = ldw(be,  t, isf32);
    if (t < 81) sWo[t]  = ldw(Wo,  t, isf32);
    if (t < 9)  sbo[t]  = ldw(bo,  t, isf32);
    if (t < 81) sWxn[t] = ldw(Wxn, t, isf32);
    if (t < 9)  sbxn[t] = ldw(bxn, t, isf32);
    for (int i = t; i < BSZ * 9; i += 256) acc[i] = 0;
    __syncthreads();

    int b = blockIdx.x;
    int r0 = bstart[b], r1 = bstart[b + 1];
    for (int i = r0 + t; i < r1; i += 256) {
        uint2 rec = perm[i];
        int   l   = (int)((rec.x >> 21) & BMASK);
        float xs  = b2f((u32)xb[rec.x & SRCMASK]);
        float a0  = b2f(rec.y & 0xffffu);
        float a1  = b2f(rec.y >> 16);
        int* ap = &acc[l * 9];
#pragma unroll
        for (int j = 0; j < 9; j++) {
            float e  = fmaf(a0, sWe[2 * j], fmaf(a1, sWe[2 * j + 1], sbe[j]));
            float hh = fmaf(xs, sWx[j], sbx[j]);
            atomicAdd(&ap[j], fx(hh * e));     // native ds_add_u32
        }
    }
    __syncthreads();

    for (int l = t; l < BSZ; l += 256) {
        int n = b * BSZ + l;
        if (n >= NNODES) break;
        float av[9];
#pragma unroll
        for (int j = 0; j < 9; j++) av[j] = (float)acc[l * 9 + j] * FXINV;
        float o[9];
#pragma unroll
        for (int k = 0; k < 9; k++) {
            float v = sbo[k];
#pragma unroll
            for (int j = 0; j < 9; j++) v = fmaf(av[j], sWo[k * 9 + j], v);
            o[k] = fmaxf(v, 0.f);
        }
        u16 hv[9];
#pragma unroll
        for (int j = 0; j < 9; j++) {
            float v = sbxn[j];
#pragma unroll
            for (int k = 0; k < 9; k++) v = fmaf(o[k], sWxn[j * 9 + k], v);
            hv[j] = f2b(v);
        }
        uint4 q;
        q.x = (u32)hv[0] | ((u32)hv[1] << 16);
        q.y = (u32)hv[2] | ((u32)hv[3] << 16);
        q.z = (u32)hv[4] | ((u32)hv[5] << 16);
        q.w = (u32)hv[6] | ((u32)hv[7] << 16);
        hA[n] = q;
        hB[n] = hv[8];
    }
}

// ---- layers 2/3: bucket-pair cohort sweep, gather 16B+2B, fx LDS acc ----
// Grid EGRID=1465 < residency cap (8 blocks/CU x 256 CU): ALL blocks start
// at t=0 with equal work -> src-sorted gathers advance in loose lockstep ->
// live hA window fits per-XCD L2.

template <int OUTF, bool FUSE_NEXT>
__global__ __launch_bounds__(256) void k_eagg(
        const int* __restrict__ bstart, const uint2* __restrict__ perm,
        const uint4* __restrict__ hA, const u16* __restrict__ hB,
        const void* We, const void* be, const void* Wo, const void* bo,
        const void* Wxn, const void* bxn,
        uint4* __restrict__ oA, u16* __restrict__ oB,
        const int* __restrict__ flag) {
    __shared__ int acc[BSZ * 9];
    __shared__ float sWe[18], sbe[9], sWo[OUTF * 9], sbo[OUTF];
    __shared__ float sWxn[FUSE_NEXT ? 81 : 1], sbxn[FUSE_NEXT ? 9 : 1];
    int isf32 = *flag;
    int t = threadIdx.x;
    if (t < 18)       sWe[t] = ldw(We, t, isf32);
    if (t < 9)        sbe[t] = ldw(be, t, isf32);
    if (t < OUTF * 9) sWo[t] = ldw(Wo, t, isf32);
    if (t < OUTF)     sbo[t] = ldw(bo, t, isf32);
    if constexpr (FUSE_NEXT) {
        if (t < 81) sWxn[t] = ldw(Wxn, t, isf32);
        if (t < 9)  sbxn[t] = ldw(bxn, t, isf32);
    }
    __syncthreads();

#pragma unroll 1
    for (int half = 0; half < 2; half++) {
        int b = blockIdx.x * 2 + half;
        if (b >= NBUCK) break;            // uniform per block

        for (int i = t; i < BSZ * 9; i += 256) acc[i] = 0;
        __syncthreads();

        int r0 = bstart[b], r1 = bstart[b + 1];
        for (int i = r0 + t; i < r1; i += 256) {
            uint2 rec = perm[i];
            int   s   = (int)(rec.x & SRCMASK);
            int   l   = (int)((rec.x >> 21) & BMASK);
            float a0  = b2f(rec.y & 0xffffu);
            float a1  = b2f(rec.y >> 16);
            uint4 qa  = hA[s];
            u32   qb  = (u32)hB[s];
            float ev[9];
#pragma unroll
            for (int j = 0; j < 9; j++)
                ev[j] = fmaf(a0, sWe[2 * j], fmaf(a1, sWe[2 * j + 1], sbe[j]));
            float h[9];
            h[0] = b2f(qa.x & 0xffffu); h[1] = b2f(qa.x >> 16);
            h[2] = b2f(qa.y & 0xffffu); h[3] = b2f(qa.y >> 16);
            h[4] = b2f(qa.z & 0xffffu); h[5] = b2f(qa.z >> 16);
            h[6] = b2f(qa.w & 0xffffu); h[7] = b2f(qa.w >> 16);
            h[8] = b2f(qb);
            int* ap = &acc[l * 9];
#pragma unroll
            for (int j = 0; j < 9; j++)
                atomicAdd(&ap[j], fx(h[j] * ev[j]));
        }
        __syncthreads();

        for (int l = t; l < BSZ; l += 256) {
            int n = b * BSZ + l;
            if (n >= NNODES) break;
            float av[9];
#pragma unroll
            for (int j = 0; j < 9; j++) av[j] = (float)acc[l * 9 + j] * FXINV;
            float o[OUTF];
#pragma unroll
            for (int k = 0; k < OUTF; k++) {
                float v = sbo[k];
#pragma unroll
                for (int j = 0; j < 9; j++) v = fmaf(av[j], sWo[k * 9 + j], v);
                o[k] = fmaxf(v, 0.f);
            }
            if constexpr (FUSE_NEXT) {
                u16 hv[9];
#pragma unroll
                for (int j = 0; j < 9; j++) {
                    float v = sbxn[j];
#pragma unroll
                    for (int k = 0; k < OUTF; k++) v = fmaf(o[k], sWxn[j * 9 + k], v);
                    hv[j] = f2b(v);
                }
                uint4 q;
                q.x = (u32)hv[0] | ((u32)hv[1] << 16);
                q.y = (u32)hv[2] | ((u32)hv[3] << 16);
                q.z = (u32)hv[4] | ((u32)hv[5] << 16);
                q.w = (u32)hv[6] | ((u32)hv[7] << 16);
                oA[n] = q;
                oB[n] = hv[8];
            } else {
                uint2 q;
                q.x = (u32)f2b(o[0]) | ((u32)f2b(o[1]) << 16);
                q.y = (u32)f2b(o[2]) | ((u32)f2b(o[3]) << 16);
                ((uint2*)oA)[n] = q;   // f table: 8B/node
            }
        }
        __syncthreads();   // acc re-zeroed next half only after all reads
    }
}

// ---------------- head MLP + log_softmax ----------------

__global__ __launch_bounds__(256) void k_head(
        const u16* __restrict__ f,
        const void* W1, const void* b1, const void* W2, const void* b2,
        void* __restrict__ out, const int* __restrict__ flag) {
    __shared__ float sW1[192], sb1[8], sW2[32], sb2[4];
    int isf32 = *flag;
    int t = threadIdx.x;
    if (t < 192) sW1[t] = ldw(W1, t, isf32);
    if (t < 8)   sb1[t] = ldw(b1, t, isf32);
    if (t < 32)  sW2[t] = ldw(W2, t, isf32);
    if (t < 4)   sb2[t] = ldw(b2, t, isf32);
    __syncthreads();

    int tr = blockIdx.x * 256 + t;
    if (tr >= NTRACK) return;

    const uint4* fp = (const uint4*)(f + (size_t)tr * 24);
    uint4 A = fp[0], B = fp[1], C = fp[2];
    u32 w[12] = {A.x, A.y, A.z, A.w, B.x, B.y, B.z, B.w, C.x, C.y, C.z, C.w};
    float in[24];
#pragma unroll
    for (int i = 0; i < 12; i++) {
        in[2 * i]     = b2f(w[i] & 0xffffu);
        in[2 * i + 1] = b2f(w[i] >> 16);
    }

    float z1[8];
#pragma unroll
    for (int o = 0; o < 8; o++) {
        float v = sb1[o];
#pragma unroll
        for (int i = 0; i < 24; i++) v = fmaf(in[i], sW1[o * 24 + i], v);
        z1[o] = fmaxf(v, 0.f);
    }
    float z2[4];
#pragma unroll
    for (int c = 0; c < 4; c++) {
        float v = sb2[c];
#pragma unroll
        for (int o = 0; o < 8; o++) v = fmaf(z1[o], sW2[c * 8 + o], v);
        z2[c] = v;
    }
    float m = fmaxf(fmaxf(z2[0], z2[1]), fmaxf(z2[2], z2[3]));
    float s = 0.f;
#pragma unroll
    for (int c = 0; c < 4; c++) s += expf(z2[c] - m);
    float l = logf(s) + m;

    if (isf32) {
        float4 q; q.x = z2[0] - l; q.y = z2[1] - l; q.z = z2[2] - l; q.w = z2[3] - l;
        ((float4*)((float*)out + (size_t)tr * 4))[0] = q;
    } else {
        uint2 q;
        q.x = (u32)f2b(z2[0] - l) | ((u32)f2b(z2[1] - l) << 16);
        q.y = (u32)f2b(z2[2] - l) | ((u32)f2b(z2[3] - l) << 16);
        ((uint2*)((u16*)out + (size_t)tr * 4))[0] = q;
    }
}

// ---------------- host ----------------

extern "C" void kernel_launch(void* const* d_in, const int* in_sizes, int n_in,
                              void* d_out, int out_size, void* d_ws, size_t ws_size,
                              hipStream_t stream) {
    const void* X    = d_in[0];
    const int* eidx  = (const int*)d_in[1];
    const void* eattr= d_in[2];
    const void *WX1 = d_in[3],  *BX1 = d_in[4];
    const void *WE1 = d_in[5],  *BE1 = d_in[6];
    const void *WO1 = d_in[7],  *BO1 = d_in[8];
    const void *WX2 = d_in[9],  *BX2 = d_in[10];
    const void *WE2 = d_in[11], *BE2 = d_in[12];
    const void *WO2 = d_in[13], *BO2 = d_in[14];
    const void *WX3 = d_in[15], *BX3 = d_in[16];
    const void *WE3 = d_in[17], *BE3 = d_in[18];
    const void *WO3 = d_in[19], *BO3 = d_in[20];
    const void *W1  = d_in[21], *B1  = d_in[22];
    const void *W2  = d_in[23], *B2  = d_in[24];

    const int* src = eidx;
    const int* dst = eidx + NEDGES;

    // workspace layout (~189 MB)
    char* w = (char*)d_ws;
    size_t off = 0;
    auto take = [&](size_t bytes) -> void* {
        void* p = w + off;
        off += (bytes + 255) & ~(size_t)255;
        return p;
    };
    int*   flag   = (int*)take(256);
    int*   bstart = (int*)take((size_t)(NBUCK + 1) * 4);
    u16*   cnt    = (u16*)take((size_t)PBLK * NBUCK * 2);   // 17.2 MB
    u16*   offm   = (u16*)take((size_t)PBLK * NBUCK * 2);   // 17.2 MB
    u16*   st     = (u16*)take((size_t)NSEG * NBUCK * 2);   // 188 KB
    u32*   segb   = (u32*)take((size_t)NSEG * NBUCK * 4);   // 375 KB
    u16*   xb     = (u16*)take((size_t)NNODES * 2);         // 3 MB bf16 x
    uint2* perm   = (uint2*)take((size_t)NEDGES * 8);       // 96 MB exact
    uint4* hA2    = (uint4*)take((size_t)NNODES * 16);      // 24 MB
    u16*   hB2    = (u16*)take((size_t)NNODES * 2);         // 3 MB
    uint4* hA3    = (uint4*)take((size_t)NNODES * 16);      // 24 MB
    u16*   hB3    = (u16*)take((size_t)NNODES * 2);         // 3 MB
    u16*   f      = (u16*)hA2;  // layer-3 output (12 MB) reuses hA2 (dead by then)
    (void)ws_size; (void)n_in; (void)in_sizes; (void)out_size;

    const int NB = (NNODES + 255) / 256;
    const int TB = (NTRACK + 255) / 256;

    k_detect <<<1,    64,  0, stream>>>((const u16*)BX1, (const u16*)BE1, (const u16*)BO1,
                                        (const u16*)BX2, (const u16*)BE2, (const u16*)B1, flag);
    k_xcast  <<<NB,   256, 0, stream>>>(X, xb, flag);
    k_hist   <<<PBLK, 512, 0, stream>>>(dst, cnt);
    k_mscanA <<<NSEG * NTILE, 64, 0, stream>>>(cnt, offm, st);
    k_mscanB <<<1,    256, 0, stream>>>(st, bstart, segb);
    k_part   <<<PBLK, 512, 0, stream>>>(src, dst, eattr, cnt, offm, segb, perm, flag);
    k_srt    <<<NBUCK,256, 0, stream>>>(bstart, perm);

    k_eagg1        <<<NBUCK, 256, 0, stream>>>(bstart, perm, xb,
                                               WX1, BX1, WE1, BE1, WO1, BO1, WX2, BX2,
                                               hA2, hB2, flag);
    k_eagg<9,true> <<<EGRID, 256, 0, stream>>>(bstart, perm, hA2, hB2,
                                               WE2, BE2, WO2, BO2, WX3, BX3,
                                               hA3, hB3, flag);
    k_eagg<4,false><<<EGRID, 256, 0, stream>>>(bstart, perm, hA3, hB3,
                                               WE3, BE3, WO3, BO3, WO3, BO3,
                                               (uint4*)f, (u16*)f, flag);
    k_head         <<<TB,    256, 0, stream>>>(f, W1, B1, W2, B2, d_out, flag);
}

// Round 6
// 952.969 us; speedup vs baseline: 1.1415x; 1.0657x over previous
//
#include <hip/hip_runtime.h>
#include <hip/hip_bf16.h>

// trackletGNN: 3x edge-conv + MLP head.
// R13: fix k_part's cross-XCD partial-line write amplification.
// R12 post-mortem: cohort sweep weakly confirmed (FETCH 885->740MB, 247->213us)
// but eagg2/3 now sit AT the structural wall: 12M x 64B random fills at the
// measured ~3.7TB/s fill ceiling = 208us ~= 213 measured. Cooperative
// slice-sync refuted by arithmetic (all-bucket acc = 54MB > 40.9MB LDS).
// R13 attacks the other ~590us: k_part writes 11-byte per-(chunk,bucket)
// runs; adjacent chunks dispatch to DIFFERENT XCDs (round-robin) -> every
// 64B perm line assembled cross-XCD -> partial-line evictions (R9: WRITE
// 246MB vs 96 ideal + ~90MB RMW fetch). Fix: bijective XCD swizzle of the
// chunk assignment so co-resident same-XCD blocks own CONSECUTIVE chunks;
// each perm line completes inside one XCD's L2 window. Also: wave-shuffle
// scan in k_part (~20 barriers vs ~108) and 512-thread k_srt.
// Bit-identical output (fixed-point adds order-independent; only block->
// chunk mapping and issue order change).

#define NNODES 1500000
#define NEDGES 12000000
#define NTRACK 250000
#define BSH    9           // log2(bucket size)
#define BSZ    512         // nodes per agg bucket
#define BMASK  511u
#define NBUCK  2930        // ceil(NNODES/512)
#define EGRID  1465        // eagg l2/l3 blocks (bucket pairs, all-resident)
#define PCHUNK 4096        // edges per k_part block (LDS-sorted)
#define PBLK   2930        // ceil(NEDGES/PCHUNK)
#define NSEG   32          // chunk segments for the column scan
#define SEGC   92          // chunks per segment (32*92 >= 2930)
#define NTILE  46          // bucket tiles of 64 ((2930+63)/64)
#define SRCMASK 0x1FFFFFu  // 21 bits
#define NSLICE 48          // src slices (src>>15, 512KB of hA each)
#define SRTR   10          // k_srt records/thread at 512 thr (runs to 5120)
#define FXSCALE 16777216.f // 2^24
#define FXINV   (1.f / 16777216.f)

typedef unsigned int   u32;
typedef unsigned short u16;

static __device__ __forceinline__ float b2f(u32 v) {
    union { float f; u32 u; } x; x.u = v << 16; return x.f;
}
static __device__ __forceinline__ u16 f2b(float f) {
    __hip_bfloat16 h = __float2bfloat16(f);
    return *reinterpret_cast<u16*>(&h);
}
static __device__ __forceinline__ float ldw(const void* p, int i, int isf32) {
    return isf32 ? ((const float*)p)[i] : b2f((u32)((const u16*)p)[i]);
}
static __device__ __forceinline__ int fx(float f) {
    return (int)rintf(f * FXSCALE);
}

// ---------------- dtype probe ----------------

__global__ void k_detect(const u16* a, const u16* b, const u16* c,
                         const u16* d, const u16* e, const u16* f,
                         int* flag) {
    if (blockIdx.x == 0 && threadIdx.x == 0) {
        int isf32 = 0;
        const u16* ps[6] = {a, b, c, d, e, f};
        const int  ns[6] = {9, 9, 9, 9, 9, 8};
        for (int k = 0; k < 6; k++)
            for (int i = 0; i < ns[k]; i++) {
                float v = b2f((u32)ps[k][i]);
                if (!(fabsf(v) < 1.0e3f)) isf32 = 1;   // catches NaN/Inf too
            }
        *flag = isf32;
    }
}

// ------------- x -> bf16 table (3 MB, fits per-XCD L2 for layer 1) -------

__global__ __launch_bounds__(256) void k_xcast(const void* __restrict__ x,
                                               u16* __restrict__ xb,
                                               const int* __restrict__ flag) {
    int isf32 = *flag;
    int n = blockIdx.x * 256 + threadIdx.x;
    if (n < NNODES)
        xb[n] = isf32 ? f2b(((const float*)x)[n]) : ((const u16*)x)[n];
}

// ------- per-chunk bucket histogram -> cnt[chunk][bucket] (u16) ---------

__global__ __launch_bounds__(512) void k_hist(const int* __restrict__ dst,
                                              u16* __restrict__ cnt) {
    __shared__ u32 h[NBUCK];
    int t = threadIdx.x;
    int chunk = blockIdx.x;
    int c0 = chunk * PCHUNK;
    for (int b = t; b < NBUCK; b += 512) h[b] = 0;
    __syncthreads();
#pragma unroll
    for (int k = 0; k < 8; k++) {
        int e = c0 + k * 512 + t;
        if (e < NEDGES) atomicAdd(&h[((u32)dst[e]) >> BSH], 1u);
    }
    __syncthreads();
    size_t row = (size_t)chunk * NBUCK;
    for (int b = t; b < NBUCK; b += 512) cnt[row + b] = (u16)h[b];
}

// -- column scan over chunks (per segment): off[chunk][b], st[seg][b] ----

__global__ __launch_bounds__(64) void k_mscanA(const u16* __restrict__ cnt,
                                               u16* __restrict__ offm,
                                               u16* __restrict__ st) {
    int seg  = blockIdx.x / NTILE;
    int tile = blockIdx.x % NTILE;
    int b = tile * 64 + threadIdx.x;
    if (b >= NBUCK) return;
    int cS = seg * SEGC;
    int cE = cS + SEGC; if (cE > PBLK) cE = PBLK;
    u32 run = 0;
#pragma unroll 4
    for (int c = cS; c < cE; c++) {
        size_t idx = (size_t)c * NBUCK + b;
        u32 v = (u32)cnt[idx];
        offm[idx] = (u16)run;
        run += v;
    }
    st[(size_t)seg * NBUCK + b] = (u16)run;
}

// -- combine: bucket totals -> bstart[], per-seg bases (bstart folded) ---

__global__ __launch_bounds__(256) void k_mscanB(const u16* __restrict__ st,
                                                int* __restrict__ bstart,
                                                u32* __restrict__ segb) {
    __shared__ u32 sd[256];
    __shared__ u32 carry;
    int t = threadIdx.x;
    if (t == 0) carry = 0;
    __syncthreads();
    for (int c0 = 0; c0 < NBUCK; c0 += 256) {
        int b = c0 + t;
        u32 tot = 0;
        if (b < NBUCK)
#pragma unroll
            for (int s = 0; s < NSEG; s++) tot += (u32)st[(size_t)s * NBUCK + b];
        sd[t] = tot; __syncthreads();
        for (int o = 1; o < 256; o <<= 1) {
            u32 a = (t >= o) ? sd[t - o] : 0;
            __syncthreads();
            sd[t] += a;
            __syncthreads();
        }
        u32 excl = carry + sd[t] - tot;
        if (b < NBUCK) {
            bstart[b] = (int)excl;
            u32 r = excl;
#pragma unroll
            for (int s = 0; s < NSEG; s++) {
                segb[(size_t)s * NBUCK + b] = r;
                r += (u32)st[(size_t)s * NBUCK + b];
            }
        }
        __syncthreads();
        if (t == 255) carry += sd[255];
        __syncthreads();
    }
    if (t == 0) bstart[NBUCK] = NEDGES;
}

// ---- partition: precomputed offsets, LDS counting sort, ordered flush ----
// LDS: cur 11.7K + gbA 11.7K + rec 32K + bid 8K = 63.4KB (static, fits).
// Zero global atomics. XCD-swizzled chunk assignment: co-resident same-XCD
// blocks own consecutive chunks -> perm lines complete inside one L2.

__global__ __launch_bounds__(512) void k_part(const int* __restrict__ src,
                                              const int* __restrict__ dst,
                                              const void* __restrict__ attr,
                                              const u16* __restrict__ cnt,
                                              const u16* __restrict__ offm,
                                              const u32* __restrict__ segb,
                                              uint2* __restrict__ perm,
                                              const int* __restrict__ flag) {
    __shared__ u32   cur[NBUCK];    // cnt -> local excl start -> cursor
    __shared__ u32   gbA[NBUCK];    // global base minus local start
    __shared__ uint2 rec[PCHUNK];   // bucket-grouped records
    __shared__ u16   bid[PCHUNK];   // per-slot bucket id
    __shared__ u32   wsum[8];
    __shared__ u32   carryS;
    int isf32 = *flag;
    int t = threadIdx.x;

    // bijective XCD swizzle (PBLK = 2930 = 8*366 + 2): XCD x<2 owns 367
    // consecutive chunks, x>=2 owns 366. blockIdx b -> (x = b&7, k = b>>3).
    int bx = blockIdx.x & 7, bk = blockIdx.x >> 3;
    int chunk = ((bx < 2) ? bx * 367 : 2 * 367 + (bx - 2) * 366) + bk;

    int seg = chunk / SEGC;
    int c0 = chunk * PCHUNK;
    int chunkN = NEDGES - c0; if (chunkN > PCHUNK) chunkN = PCHUNK;
    size_t row = (size_t)chunk * NBUCK;

    // load this chunk's per-bucket counts
    for (int b = t; b < NBUCK; b += 512) cur[b] = (u32)cnt[row + b];
    if (t == 0) carryS = 0;
    __syncthreads();

    // local exclusive scan (in place), wave-shuffle version
    int lane = t & 63, wv = t >> 6;
    for (int b0 = 0; b0 < NBUCK; b0 += 512) {
        int b = b0 + t;
        u32 v = (b < NBUCK) ? cur[b] : 0;
        u32 xs = v;
#pragma unroll
        for (int o = 1; o < 64; o <<= 1) {
            u32 y = __shfl_up(xs, o, 64);
            if (lane >= o) xs += y;
        }
        if (lane == 63) wsum[wv] = xs;
        __syncthreads();
        if (t < 8) {
            u32 ws = wsum[t];
#pragma unroll
            for (int o = 1; o < 8; o <<= 1) {
                u32 y = __shfl_up(ws, o, 8);
                if (t >= o) ws += y;
            }
            wsum[t] = ws;
        }
        __syncthreads();
        u32 incl = xs + (wv ? wsum[wv - 1] : 0);
        if (b < NBUCK) cur[b] = carryS + incl - v;
        __syncthreads();               // all excl computed before carry bump
        if (t == 0) carryS += wsum[7];
        __syncthreads();
    }

    // global base minus local start (all precomputed, coalesced reads)
    for (int b = t; b < NBUCK; b += 512)
        gbA[b] = segb[(size_t)seg * NBUCK + b] + (u32)offm[row + b] - cur[b];
    __syncthreads();

    // fused edge pass: read, pack, scatter into LDS by bucket
#pragma unroll
    for (int k = 0; k < 8; k++) {
        int e = c0 + k * 512 + t;
        if (e < NEDGES) {
            u32 d = (u32)dst[e];
            u32 s = (u32)src[e];
            u32 fb = d >> BSH;
            u32 ap;
            if (isf32) {
                float2 a = ((const float2*)attr)[e];
                ap = (u32)f2b(a.x) | ((u32)f2b(a.y) << 16);
            } else {
                ap = ((const u32*)attr)[e];
            }
            int slot = (int)atomicAdd(&cur[fb], 1u);
            uint2 r; r.x = s | ((d & BMASK) << 21); r.y = ap;
            rec[slot] = r;
            bid[slot] = (u16)fb;
        }
    }
    __syncthreads();

    // ordered flush: ascending slot = ascending global address per bucket
#pragma unroll
    for (int j = 0; j < 8; j++) {
        int s = j * 512 + t;
        if (s < chunkN) {
            u32 fb = (u32)bid[s];
            perm[gbA[fb] + s] = rec[s];
        }
    }
}

// ---- k_srt: in-place per-bucket counting sort by src slice (src>>15) ----
// Gives the eagg sweep its monotone gather order (cohort L2 window) and
// keeps the 3MB hB table L2-resident.

__global__ __launch_bounds__(512) void k_srt(const int* __restrict__ bstart,
                                             uint2* __restrict__ perm) {
    __shared__ int h[NSLICE];
    int t = threadIdx.x;
    int b = blockIdx.x;
    int r0 = bstart[b], r1 = bstart[b + 1];
    int len = r1 - r0;
    if (len <= 0) return;                 // uniform branch
    if (len > SRTR * 512) return;         // safety: leave bucket unsorted
    if (t < NSLICE) h[t] = 0;
    __syncthreads();

    uint2 r[SRTR];
#pragma unroll
    for (int k = 0; k < SRTR; k++) {
        int i = r0 + k * 512 + t;
        if (i < r1) {
            r[k] = perm[i];
            atomicAdd(&h[(r[k].x & SRCMASK) >> 15], 1);
        } else {
            r[k].x = 0xFFFFFFFFu;         // rec.x < 2^30 => safe sentinel
        }
    }
    __syncthreads();                      // all reads done before any write

    if (t == 0) {
        int s = 0;
        for (int k = 0; k < NSLICE; k++) { int c = h[k]; h[k] = s; s += c; }
    }
    __syncthreads();

#pragma unroll
    for (int k = 0; k < SRTR; k++) {
        if (r[k].x != 0xFFFFFFFFu) {
            int slot = atomicAdd(&h[(r[k].x & SRCMASK) >> 15], 1);
            perm[r0 + slot] = r[k];       // scatter within 36KB window: L2-merged
        }
    }
}

// ---- layer 1 (edge-centric): gather bf16 x (L2-resident), fx LDS acc ----

__global__ __launch_bounds__(256) void k_eagg1(
        const int* __restrict__ bstart, const uint2* __restrict__ perm,
        const u16* __restrict__ xb,
        const void* Wx, const void* bx, const void* We, const void* be,
        const void* Wo, const void* bo, const void* Wxn, const void* bxn,
        uint4* __restrict__ hA, u16* __restrict__ hB,
        const int* __restrict__ flag) {
    __shared__ int acc[BSZ * 9];
    __shared__ float sWx[9], sbx[9], sWe[18], sbe[9], sWo[81], sbo[9], sWxn[81], sbxn[9];
    int isf32 = *flag;
    int t = threadIdx.x;
    if (t < 9)  sWx[t]  = ldw(Wx,  t, isf32);
    if (t < 9)  sbx[t]  = ldw(bx,  t, isf32);
    if (t < 18) sWe[t]  = ldw(We,  t, isf32);
    if (t < 9)  sbe[t]  = ldw(be,  t, isf32);
    if (t < 81) sWo[t]  = ldw(Wo,  t, isf32);
    if (t < 9)  sbo[t]  = ldw(bo,  t, isf32);
    if (t < 81) sWxn[t] = ldw(Wxn, t, isf32);
    if (t < 9)  sbxn[t] = ldw(bxn, t, isf32);
    for (int i = t; i < BSZ * 9; i += 256) acc[i] = 0;
    __syncthreads();

    int b = blockIdx.x;
    int r0 = bstart[b], r1 = bstart[b + 1];
    for (int i = r0 + t; i < r1; i += 256) {
        uint2 rec = perm[i];
        int   l   = (int)((rec.x >> 21) & BMASK);
        float xs  = b2f((u32)xb[rec.x & SRCMASK]);
        float a0  = b2f(rec.y & 0xffffu);
        float a1  = b2f(rec.y >> 16);
        int* ap = &acc[l * 9];
#pragma unroll
        for (int j = 0; j < 9; j++) {
            float e  = fmaf(a0, sWe[2 * j], fmaf(a1, sWe[2 * j + 1], sbe[j]));
            float hh = fmaf(xs, sWx[j], sbx[j]);
            atomicAdd(&ap[j], fx(hh * e));     // native ds_add_u32
        }
    }
    __syncthreads();

    for (int l = t; l < BSZ; l += 256) {
        int n = b * BSZ + l;
        if (n >= NNODES) break;
        float av[9];
#pragma unroll
        for (int j = 0; j < 9; j++) av[j] = (float)acc[l * 9 + j] * FXINV;
        float o[9];
#pragma unroll
        for (int k = 0; k < 9; k++) {
            float v = sbo[k];
#pragma unroll
            for (int j = 0; j < 9; j++) v = fmaf(av[j], sWo[k * 9 + j], v);
            o[k] = fmaxf(v, 0.f);
        }
        u16 hv[9];
#pragma unroll
        for (int j = 0; j < 9; j++) {
            float v = sbxn[j];
#pragma unroll
            for (int k = 0; k < 9; k++) v = fmaf(o[k], sWxn[j * 9 + k], v);
            hv[j] = f2b(v);
        }
        uint4 q;
        q.x = (u32)hv[0] | ((u32)hv[1] << 16);
        q.y = (u32)hv[2] | ((u32)hv[3] << 16);
        q.z = (u32)hv[4] | ((u32)hv[5] << 16);
        q.w = (u32)hv[6] | ((u32)hv[7] << 16);
        hA[n] = q;
        hB[n] = hv[8];
    }
}

// ---- layers 2/3: bucket-pair cohort sweep, gather 16B+2B, fx LDS acc ----

template <int OUTF, bool FUSE_NEXT>
__global__ __launch_bounds__(256) void k_eagg(
        const int* __restrict__ bstart, const uint2* __restrict__ perm,
        const uint4* __restrict__ hA, const u16* __restrict__ hB,
        const void* We, const void* be, const void* Wo, const void* bo,
        const void* Wxn, const void* bxn,
        uint4* __restrict__ oA, u16* __restrict__ oB,
        const int* __restrict__ flag) {
    __shared__ int acc[BSZ * 9];
    __shared__ float sWe[18], sbe[9], sWo[OUTF * 9], sbo[OUTF];
    __shared__ float sWxn[FUSE_NEXT ? 81 : 1], sbxn[FUSE_NEXT ? 9 : 1];
    int isf32 = *flag;
    int t = threadIdx.x;
    if (t < 18)       sWe[t] = ldw(We, t, isf32);
    if (t < 9)        sbe[t] = ldw(be, t, isf32);
    if (t < OUTF * 9) sWo[t] = ldw(Wo, t, isf32);
    if (t < OUTF)     sbo[t] = ldw(bo, t, isf32);
    if constexpr (FUSE_NEXT) {
        if (t < 81) sWxn[t] = ldw(Wxn, t, isf32);
        if (t < 9)  sbxn[t] = ldw(bxn, t, isf32);
    }
    __syncthreads();

#pragma unroll 1
    for (int half = 0; half < 2; half++) {
        int b = blockIdx.x * 2 + half;
        if (b >= NBUCK) break;            // uniform per block

        for (int i = t; i < BSZ * 9; i += 256) acc[i] = 0;
        __syncthreads();

        int r0 = bstart[b], r1 = bstart[b + 1];
        for (int i = r0 + t; i < r1; i += 256) {
            uint2 rec = perm[i];
            int   s   = (int)(rec.x & SRCMASK);
            int   l   = (int)((rec.x >> 21) & BMASK);
            float a0  = b2f(rec.y & 0xffffu);
            float a1  = b2f(rec.y >> 16);
            uint4 qa  = hA[s];
            u32   qb  = (u32)hB[s];
            float ev[9];
#pragma unroll
            for (int j = 0; j < 9; j++)
                ev[j] = fmaf(a0, sWe[2 * j], fmaf(a1, sWe[2 * j + 1], sbe[j]));
            float h[9];
            h[0] = b2f(qa.x & 0xffffu); h[1] = b2f(qa.x >> 16);
            h[2] = b2f(qa.y & 0xffffu); h[3] = b2f(qa.y >> 16);
            h[4] = b2f(qa.z & 0xffffu); h[5] = b2f(qa.z >> 16);
            h[6] = b2f(qa.w & 0xffffu); h[7] = b2f(qa.w >> 16);
            h[8] = b2f(qb);
            int* ap = &acc[l * 9];
#pragma unroll
            for (int j = 0; j < 9; j++)
                atomicAdd(&ap[j], fx(h[j] * ev[j]));
        }
        __syncthreads();

        for (int l = t; l < BSZ; l += 256) {
            int n = b * BSZ + l;
            if (n >= NNODES) break;
            float av[9];
#pragma unroll
            for (int j = 0; j < 9; j++) av[j] = (float)acc[l * 9 + j] * FXINV;
            float o[OUTF];
#pragma unroll
            for (int k = 0; k < OUTF; k++) {
                float v = sbo[k];
#pragma unroll
                for (int j = 0; j < 9; j++) v = fmaf(av[j], sWo[k * 9 + j], v);
                o[k] = fmaxf(v, 0.f);
            }
            if constexpr (FUSE_NEXT) {
                u16 hv[9];
#pragma unroll
                for (int j = 0; j < 9; j++) {
                    float v = sbxn[j];
#pragma unroll
                    for (int k = 0; k < OUTF; k++) v = fmaf(o[k], sWxn[j * 9 + k], v);
                    hv[j] = f2b(v);
                }
                uint4 q;
                q.x = (u32)hv[0] | ((u32)hv[1] << 16);
                q.y = (u32)hv[2] | ((u32)hv[3] << 16);
                q.z = (u32)hv[4] | ((u32)hv[5] << 16);
                q.w = (u32)hv[6] | ((u32)hv[7] << 16);
                oA[n] = q;
                oB[n] = hv[8];
            } else {
                uint2 q;
                q.x = (u32)f2b(o[0]) | ((u32)f2b(o[1]) << 16);
                q.y = (u32)f2b(o[2]) | ((u32)f2b(o[3]) << 16);
                ((uint2*)oA)[n] = q;   // f table: 8B/node
            }
        }
        __syncthreads();   // acc re-zeroed next half only after all reads
    }
}

// ---------------- head MLP + log_softmax ----------------

__global__ __launch_bounds__(256) void k_head(
        const u16* __restrict__ f,
        const void* W1, const void* b1, const void* W2, const void* b2,
        void* __restrict__ out, const int* __restrict__ flag) {
    __shared__ float sW1[192], sb1[8], sW2[32], sb2[4];
    int isf32 = *flag;
    int t = threadIdx.x;
    if (t < 192) sW1[t] = ldw(W1, t, isf32);
    if (t < 8)   sb1[t] = ldw(b1, t, isf32);
    if (t < 32)  sW2[t] = ldw(W2, t, isf32);
    if (t < 4)   sb2[t] = ldw(b2, t, isf32);
    __syncthreads();

    int tr = blockIdx.x * 256 + t;
    if (tr >= NTRACK) return;

    const uint4* fp = (const uint4*)(f + (size_t)tr * 24);
    uint4 A = fp[0], B = fp[1], C = fp[2];
    u32 w[12] = {A.x, A.y, A.z, A.w, B.x, B.y, B.z, B.w, C.x, C.y, C.z, C.w};
    float in[24];
#pragma unroll
    for (int i = 0; i < 12; i++) {
        in[2 * i]     = b2f(w[i] & 0xffffu);
        in[2 * i + 1] = b2f(w[i] >> 16);
    }

    float z1[8];
#pragma unroll
    for (int o = 0; o < 8; o++) {
        float v = sb1[o];
#pragma unroll
        for (int i = 0; i < 24; i++) v = fmaf(in[i], sW1[o * 24 + i], v);
        z1[o] = fmaxf(v, 0.f);
    }
    float z2[4];
#pragma unroll
    for (int c = 0; c < 4; c++) {
        float v = sb2[c];
#pragma unroll
        for (int o = 0; o < 8; o++) v = fmaf(z1[o], sW2[c * 8 + o], v);
        z2[c] = v;
    }
    float m = fmaxf(fmaxf(z2[0], z2[1]), fmaxf(z2[2], z2[3]));
    float s = 0.f;
#pragma unroll
    for (int c = 0; c < 4; c++) s += expf(z2[c] - m);
    float l = logf(s) + m;

    if (isf32) {
        float4 q; q.x = z2[0] - l; q.y = z2[1] - l; q.z = z2[2] - l; q.w = z2[3] - l;
        ((float4*)((float*)out + (size_t)tr * 4))[0] = q;
    } else {
        uint2 q;
        q.x = (u32)f2b(z2[0] - l) | ((u32)f2b(z2[1] - l) << 16);
        q.y = (u32)f2b(z2[2] - l) | ((u32)f2b(z2[3] - l) << 16);
        ((uint2*)((u16*)out + (size_t)tr * 4))[0] = q;
    }
}

// ---------------- host ----------------

extern "C" void kernel_launch(void* const* d_in, const int* in_sizes, int n_in,
                              void* d_out, int out_size, void* d_ws, size_t ws_size,
                              hipStream_t stream) {
    const void* X    = d_in[0];
    const int* eidx  = (const int*)d_in[1];
    const void* eattr= d_in[2];
    const void *WX1 = d_in[3],  *BX1 = d_in[4];
    const void *WE1 = d_in[5],  *BE1 = d_in[6];
    const void *WO1 = d_in[7],  *BO1 = d_in[8];
    const void *WX2 = d_in[9],  *BX2 = d_in[10];
    const void *WE2 = d_in[11], *BE2 = d_in[12];
    const void *WO2 = d_in[13], *BO2 = d_in[14];
    const void *WX3 = d_in[15], *BX3 = d_in[16];
    const void *WE3 = d_in[17], *BE3 = d_in[18];
    const void *WO3 = d_in[19], *BO3 = d_in[20];
    const void *W1  = d_in[21], *B1  = d_in[22];
    const void *W2  = d_in[23], *B2  = d_in[24];

    const int* src = eidx;
    const int* dst = eidx + NEDGES;

    // workspace layout (~189 MB)
    char* w = (char*)d_ws;
    size_t off = 0;
    auto take = [&](size_t bytes) -> void* {
        void* p = w + off;
        off += (bytes + 255) & ~(size_t)255;
        return p;
    };
    int*   flag   = (int*)take(256);
    int*   bstart = (int*)take((size_t)(NBUCK + 1) * 4);
    u16*   cnt    = (u16*)take((size_t)PBLK * NBUCK * 2);   // 17.2 MB
    u16*   offm   = (u16*)take((size_t)PBLK * NBUCK * 2);   // 17.2 MB
    u16*   st     = (u16*)take((size_t)NSEG * NBUCK * 2);   // 188 KB
    u32*   segb   = (u32*)take((size_t)NSEG * NBUCK * 4);   // 375 KB
    u16*   xb     = (u16*)take((size_t)NNODES * 2);         // 3 MB bf16 x
    uint2* perm   = (uint2*)take((size_t)NEDGES * 8);       // 96 MB exact
    uint4* hA2    = (uint4*)take((size_t)NNODES * 16);      // 24 MB
    u16*   hB2    = (u16*)take((size_t)NNODES * 2);         // 3 MB
    uint4* hA3    = (uint4*)take((size_t)NNODES * 16);      // 24 MB
    u16*   hB3    = (u16*)take((size_t)NNODES * 2);         // 3 MB
    u16*   f      = (u16*)hA2;  // layer-3 output (12 MB) reuses hA2 (dead by then)
    (void)ws_size; (void)n_in; (void)in_sizes; (void)out_size;

    const int NB = (NNODES + 255) / 256;
    const int TB = (NTRACK + 255) / 256;

    k_detect <<<1,    64,  0, stream>>>((const u16*)BX1, (const u16*)BE1, (const u16*)BO1,
                                        (const u16*)BX2, (const u16*)BE2, (const u16*)B1, flag);
    k_xcast  <<<NB,   256, 0, stream>>>(X, xb, flag);
    k_hist   <<<PBLK, 512, 0, stream>>>(dst, cnt);
    k_mscanA <<<NSEG * NTILE, 64, 0, stream>>>(cnt, offm, st);
    k_mscanB <<<1,    256, 0, stream>>>(st, bstart, segb);
    k_part   <<<PBLK, 512, 0, stream>>>(src, dst, eattr, cnt, offm, segb, perm, flag);
    k_srt    <<<NBUCK,512, 0, stream>>>(bstart, perm);

    k_eagg1        <<<NBUCK, 256, 0, stream>>>(bstart, perm, xb,
                                               WX1, BX1, WE1, BE1, WO1, BO1, WX2, BX2,
                                               hA2, hB2, flag);
    k_eagg<9,true> <<<EGRID, 256, 0, stream>>>(bstart, perm, hA2, hB2,
                                               WE2, BE2, WO2, BO2, WX3, BX3,
                                               hA3, hB3, flag);
    k_eagg<4,false><<<EGRID, 256, 0, stream>>>(bstart, perm, hA3, hB3,
                                               WE3, BE3, WO3, BO3, WO3, BO3,
                                               (uint4*)f, (u16*)f, flag);
    k_head         <<<TB,    256, 0, stream>>>(f, W1, B1, W2, B2, d_out, flag);
}

// Round 7
// 901.337 us; speedup vs baseline: 1.2069x; 1.0573x over previous
//
#include <hip/hip_runtime.h>
#include <hip/hip_bf16.h>

// trackletGNN: 3x edge-conv + MLP head.
// R14: (a) non-temporal streams, (b) fuse k_srt + k_eagg1.
// R13 post-mortem: XCD swizzle confirmed (-63us). eagg2/3 pinned at 212us,
// FETCH 740MB = 0.84 lines/edge. Cohort drift arithmetic (~1%) can't explain
// the weak L2 reuse -- but the 96MB perm stream + 27MB output stream per
// dispatch continuously evict the gather window from the 4MB per-XCD L2.
// Fix: perm loads + output stores use nt (evict-first); only gather tables
// stay cache-resident. Also nt on k_part/k_hist pure streams (src/dst/attr)
// to protect perm line assembly.
// Fusion: k_srt already holds each bucket's records in registers; layer-1
// aggregation is order-independent fixed point -> aggregate directly from
// registers after writing the sorted perm. Kills eagg1's separate 96MB perm
// re-read + LDS re-zero + launch. Overflow buckets (>5120 edges, ~5-sigma)
// take an unsorted streaming fallback (correct; eagg2/3 just see that
// bucket unsorted). Bit-identical output.

#define NNODES 1500000
#define NEDGES 12000000
#define NTRACK 250000
#define BSH    9           // log2(bucket size)
#define BSZ    512         // nodes per agg bucket
#define BMASK  511u
#define NBUCK  2930        // ceil(NNODES/512)
#define EGRID  1465        // eagg l2/l3 blocks (bucket pairs, all-resident)
#define PCHUNK 4096        // edges per k_part block (LDS-sorted)
#define PBLK   2930        // ceil(NEDGES/PCHUNK)
#define NSEG   32          // chunk segments for the column scan
#define SEGC   92          // chunks per segment (32*92 >= 2930)
#define NTILE  46          // bucket tiles of 64 ((2930+63)/64)
#define SRCMASK 0x1FFFFFu  // 21 bits
#define NSLICE 48          // src slices (src>>15, 512KB of hA each)
#define SRTR   10          // srtagg1 records/thread at 512 thr (runs to 5120)
#define FXSCALE 16777216.f // 2^24
#define FXINV   (1.f / 16777216.f)

typedef unsigned int   u32;
typedef unsigned short u16;
typedef u32 v2u __attribute__((ext_vector_type(2)));
typedef u32 v4u __attribute__((ext_vector_type(4)));

static __device__ __forceinline__ float b2f(u32 v) {
    union { float f; u32 u; } x; x.u = v << 16; return x.f;
}
static __device__ __forceinline__ u16 f2b(float f) {
    __hip_bfloat16 h = __float2bfloat16(f);
    return *reinterpret_cast<u16*>(&h);
}
static __device__ __forceinline__ float ldw(const void* p, int i, int isf32) {
    return isf32 ? ((const float*)p)[i] : b2f((u32)((const u16*)p)[i]);
}
static __device__ __forceinline__ int fx(float f) {
    return (int)rintf(f * FXSCALE);
}
// ---- non-temporal access helpers (nt = evict-first, keeps L2 for gathers) --
static __device__ __forceinline__ uint2 ntld2(const uint2* p) {
    v2u v = __builtin_nontemporal_load((const v2u*)p);
    uint2 r; r.x = v.x; r.y = v.y; return r;
}
static __device__ __forceinline__ int ntldi(const int* p) {
    return __builtin_nontemporal_load(p);
}
static __device__ __forceinline__ u32 ntldu(const u32* p) {
    return __builtin_nontemporal_load(p);
}
static __device__ __forceinline__ float2 ntldf2(const float2* p) {
    v2u v = __builtin_nontemporal_load((const v2u*)p);
    float2 r;
    union { float f; u32 u; } a, b;
    a.u = v.x; b.u = v.y; r.x = a.f; r.y = b.f;
    return r;
}
static __device__ __forceinline__ void ntst4(uint4* p, uint4 q) {
    v4u v; v.x = q.x; v.y = q.y; v.z = q.z; v.w = q.w;
    __builtin_nontemporal_store(v, (v4u*)p);
}
static __device__ __forceinline__ void ntst2(uint2* p, uint2 q) {
    v2u v; v.x = q.x; v.y = q.y;
    __builtin_nontemporal_store(v, (v2u*)p);
}
static __device__ __forceinline__ void ntstw(u16* p, u16 q) {
    __builtin_nontemporal_store(q, p);
}

// ---------------- dtype probe ----------------

__global__ void k_detect(const u16* a, const u16* b, const u16* c,
                         const u16* d, const u16* e, const u16* f,
                         int* flag) {
    if (blockIdx.x == 0 && threadIdx.x == 0) {
        int isf32 = 0;
        const u16* ps[6] = {a, b, c, d, e, f};
        const int  ns[6] = {9, 9, 9, 9, 9, 8};
        for (int k = 0; k < 6; k++)
            for (int i = 0; i < ns[k]; i++) {
                float v = b2f((u32)ps[k][i]);
                if (!(fabsf(v) < 1.0e3f)) isf32 = 1;   // catches NaN/Inf too
            }
        *flag = isf32;
    }
}

// ------------- x -> bf16 table (3 MB, fits per-XCD L2 for layer 1) -------

__global__ __launch_bounds__(256) void k_xcast(const void* __restrict__ x,
                                               u16* __restrict__ xb,
                                               const int* __restrict__ flag) {
    int isf32 = *flag;
    int n = blockIdx.x * 256 + threadIdx.x;
    if (n < NNODES)
        xb[n] = isf32 ? f2b(((const float*)x)[n]) : ((const u16*)x)[n];
}

// ------- per-chunk bucket histogram -> cnt[chunk][bucket] (u16) ---------

__global__ __launch_bounds__(512) void k_hist(const int* __restrict__ dst,
                                              u16* __restrict__ cnt) {
    __shared__ u32 h[NBUCK];
    int t = threadIdx.x;
    int chunk = blockIdx.x;
    int c0 = chunk * PCHUNK;
    for (int b = t; b < NBUCK; b += 512) h[b] = 0;
    __syncthreads();
#pragma unroll
    for (int k = 0; k < 8; k++) {
        int e = c0 + k * 512 + t;
        if (e < NEDGES) atomicAdd(&h[((u32)ntldi(&dst[e])) >> BSH], 1u);
    }
    __syncthreads();
    size_t row = (size_t)chunk * NBUCK;
    for (int b = t; b < NBUCK; b += 512) cnt[row + b] = (u16)h[b];
}

// -- column scan over chunks (per segment): off[chunk][b], st[seg][b] ----

__global__ __launch_bounds__(64) void k_mscanA(const u16* __restrict__ cnt,
                                               u16* __restrict__ offm,
                                               u16* __restrict__ st) {
    int seg  = blockIdx.x / NTILE;
    int tile = blockIdx.x % NTILE;
    int b = tile * 64 + threadIdx.x;
    if (b >= NBUCK) return;
    int cS = seg * SEGC;
    int cE = cS + SEGC; if (cE > PBLK) cE = PBLK;
    u32 run = 0;
#pragma unroll 4
    for (int c = cS; c < cE; c++) {
        size_t idx = (size_t)c * NBUCK + b;
        u32 v = (u32)cnt[idx];
        offm[idx] = (u16)run;
        run += v;
    }
    st[(size_t)seg * NBUCK + b] = (u16)run;
}

// -- combine: bucket totals -> bstart[], per-seg bases (bstart folded) ---

__global__ __launch_bounds__(256) void k_mscanB(const u16* __restrict__ st,
                                                int* __restrict__ bstart,
                                                u32* __restrict__ segb) {
    __shared__ u32 sd[256];
    __shared__ u32 carry;
    int t = threadIdx.x;
    if (t == 0) carry = 0;
    __syncthreads();
    for (int c0 = 0; c0 < NBUCK; c0 += 256) {
        int b = c0 + t;
        u32 tot = 0;
        if (b < NBUCK)
#pragma unroll
            for (int s = 0; s < NSEG; s++) tot += (u32)st[(size_t)s * NBUCK + b];
        sd[t] = tot; __syncthreads();
        for (int o = 1; o < 256; o <<= 1) {
            u32 a = (t >= o) ? sd[t - o] : 0;
            __syncthreads();
            sd[t] += a;
            __syncthreads();
        }
        u32 excl = carry + sd[t] - tot;
        if (b < NBUCK) {
            bstart[b] = (int)excl;
            u32 r = excl;
#pragma unroll
            for (int s = 0; s < NSEG; s++) {
                segb[(size_t)s * NBUCK + b] = r;
                r += (u32)st[(size_t)s * NBUCK + b];
            }
        }
        __syncthreads();
        if (t == 255) carry += sd[255];
        __syncthreads();
    }
    if (t == 0) bstart[NBUCK] = NEDGES;
}

// ---- partition: precomputed offsets, LDS counting sort, ordered flush ----
// LDS: cur 11.7K + gbA 11.7K + rec 32K + bid 8K = 63.4KB (static, fits).
// Zero global atomics. XCD-swizzled chunk assignment (R13, proven).

__global__ __launch_bounds__(512) void k_part(const int* __restrict__ src,
                                              const int* __restrict__ dst,
                                              const void* __restrict__ attr,
                                              const u16* __restrict__ cnt,
                                              const u16* __restrict__ offm,
                                              const u32* __restrict__ segb,
                                              uint2* __restrict__ perm,
                                              const int* __restrict__ flag) {
    __shared__ u32   cur[NBUCK];    // cnt -> local excl start -> cursor
    __shared__ u32   gbA[NBUCK];    // global base minus local start
    __shared__ uint2 rec[PCHUNK];   // bucket-grouped records
    __shared__ u16   bid[PCHUNK];   // per-slot bucket id
    __shared__ u32   wsum[8];
    __shared__ u32   carryS;
    int isf32 = *flag;
    int t = threadIdx.x;

    // bijective XCD swizzle (PBLK = 2930 = 8*366 + 2): XCD x<2 owns 367
    // consecutive chunks, x>=2 owns 366. blockIdx b -> (x = b&7, k = b>>3).
    int bx = blockIdx.x & 7, bk = blockIdx.x >> 3;
    int chunk = ((bx < 2) ? bx * 367 : 2 * 367 + (bx - 2) * 366) + bk;

    int seg = chunk / SEGC;
    int c0 = chunk * PCHUNK;
    int chunkN = NEDGES - c0; if (chunkN > PCHUNK) chunkN = PCHUNK;
    size_t row = (size_t)chunk * NBUCK;

    // load this chunk's per-bucket counts
    for (int b = t; b < NBUCK; b += 512) cur[b] = (u32)cnt[row + b];
    if (t == 0) carryS = 0;
    __syncthreads();

    // local exclusive scan (in place), wave-shuffle version
    int lane = t & 63, wv = t >> 6;
    for (int b0 = 0; b0 < NBUCK; b0 += 512) {
        int b = b0 + t;
        u32 v = (b < NBUCK) ? cur[b] : 0;
        u32 xs = v;
#pragma unroll
        for (int o = 1; o < 64; o <<= 1) {
            u32 y = __shfl_up(xs, o, 64);
            if (lane >= o) xs += y;
        }
        if (lane == 63) wsum[wv] = xs;
        __syncthreads();
        if (t < 8) {
            u32 ws = wsum[t];
#pragma unroll
            for (int o = 1; o < 8; o <<= 1) {
                u32 y = __shfl_up(ws, o, 8);
                if (t >= o) ws += y;
            }
            wsum[t] = ws;
        }
        __syncthreads();
        u32 incl = xs + (wv ? wsum[wv - 1] : 0);
        if (b < NBUCK) cur[b] = carryS + incl - v;
        __syncthreads();               // all excl computed before carry bump
        if (t == 0) carryS += wsum[7];
        __syncthreads();
    }

    // global base minus local start (all precomputed, coalesced reads)
    for (int b = t; b < NBUCK; b += 512)
        gbA[b] = segb[(size_t)seg * NBUCK + b] + (u32)offm[row + b] - cur[b];
    __syncthreads();

    // fused edge pass: read (nt streams), pack, scatter into LDS by bucket
#pragma unroll
    for (int k = 0; k < 8; k++) {
        int e = c0 + k * 512 + t;
        if (e < NEDGES) {
            u32 d = (u32)ntldi(&dst[e]);
            u32 s = (u32)ntldi(&src[e]);
            u32 fb = d >> BSH;
            u32 ap;
            if (isf32) {
                float2 a = ntldf2(&((const float2*)attr)[e]);
                ap = (u32)f2b(a.x) | ((u32)f2b(a.y) << 16);
            } else {
                ap = ntldu(&((const u32*)attr)[e]);
            }
            int slot = (int)atomicAdd(&cur[fb], 1u);
            uint2 r; r.x = s | ((d & BMASK) << 21); r.y = ap;
            rec[slot] = r;
            bid[slot] = (u16)fb;
        }
    }
    __syncthreads();

    // ordered flush: ascending slot = ascending global address per bucket
    // (cached writes: L2 assembles the 64B perm lines within the XCD window)
#pragma unroll
    for (int j = 0; j < 8; j++) {
        int s = j * 512 + t;
        if (s < chunkN) {
            u32 fb = (u32)bid[s];
            perm[gbA[fb] + s] = rec[s];
        }
    }
}

// ---- k_srtagg1: fused src-slice sort + layer-1 aggregation -------------
// Sort phase = R13 k_srt (records in registers, slot via LDS histogram).
// Agg phase consumes the SAME register-held records (order-independent
// fixed-point) -> eagg1's 96MB perm re-read + launch eliminated.

__global__ __launch_bounds__(512) void k_srtagg1(
        const int* __restrict__ bstart, uint2* __restrict__ perm,
        const u16* __restrict__ xb,
        const void* Wx, const void* bx, const void* We, const void* be,
        const void* Wo, const void* bo, const void* Wxn, const void* bxn,
        uint4* __restrict__ hA, u16* __restrict__ hB,
        const int* __restrict__ flag) {
    __shared__ int acc[BSZ * 9];
    __shared__ int h[NSLICE];
    __shared__ float sWx[9], sbx[9], sWe[18], sbe[9], sWo[81], sbo[9], sWxn[81], sbxn[9];
    int isf32 = *flag;
    int t = threadIdx.x;
    if (t < 9)  sWx[t]  = ldw(Wx,  t, isf32);
    if (t < 9)  sbx[t]  = ldw(bx,  t, isf32);
    if (t < 18) sWe[t]  = ldw(We,  t, isf32);
    if (t < 9)  sbe[t]  = ldw(be,  t, isf32);
    if (t < 81) sWo[t]  = ldw(Wo,  t, isf32);
    if (t < 9)  sbo[t]  = ldw(bo,  t, isf32);
    if (t < 81) sWxn[t] = ldw(Wxn, t, isf32);
    if (t < 9)  sbxn[t] = ldw(bxn, t, isf32);
    if (t < NSLICE) h[t] = 0;
    for (int i = t; i < BSZ * 9; i += 512) acc[i] = 0;
    __syncthreads();

    int b = blockIdx.x;
    int r0 = bstart[b], r1 = bstart[b + 1];
    int len = r1 - r0;

    if (len > 0 && len <= SRTR * 512) {
        // ---- sortable path (covers ~all buckets; mean 4096, cap 5120) ----
        uint2 r[SRTR];
#pragma unroll
        for (int k = 0; k < SRTR; k++) {
            int i = r0 + k * 512 + t;
            if (i < r1) {
                r[k] = ntld2(&perm[i]);
                atomicAdd(&h[(r[k].x & SRCMASK) >> 15], 1);
            } else {
                r[k].x = 0xFFFFFFFFu;     // rec.x < 2^30 => safe sentinel
            }
        }
        __syncthreads();                  // all reads done before any write
        if (t == 0) {
            int s = 0;
            for (int k = 0; k < NSLICE; k++) { int c = h[k]; h[k] = s; s += c; }
        }
        __syncthreads();
#pragma unroll
        for (int k = 0; k < SRTR; k++) {
            if (r[k].x != 0xFFFFFFFFu) {
                int slot = atomicAdd(&h[(r[k].x & SRCMASK) >> 15], 1);
                perm[r0 + slot] = r[k];   // cached: 36KB-window L2 assembly
            }
        }
        // ---- layer-1 aggregation from the register-held records ----
#pragma unroll
        for (int k = 0; k < SRTR; k++) {
            if (r[k].x != 0xFFFFFFFFu) {
                int   l  = (int)((r[k].x >> 21) & BMASK);
                float xs = b2f((u32)xb[r[k].x & SRCMASK]);
                float a0 = b2f(r[k].y & 0xffffu);
                float a1 = b2f(r[k].y >> 16);
                int* ap = &acc[l * 9];
#pragma unroll
                for (int j = 0; j < 9; j++) {
                    float e  = fmaf(a0, sWe[2 * j], fmaf(a1, sWe[2 * j + 1], sbe[j]));
                    float hh = fmaf(xs, sWx[j], sbx[j]);
                    atomicAdd(&ap[j], fx(hh * e));   // native ds_add_u32
                }
            }
        }
    } else if (len > 0) {
        // ---- overflow fallback (~5-sigma): unsorted streaming aggregate ----
        for (int i = r0 + t; i < r1; i += 512) {
            uint2 rec = perm[i];
            int   l  = (int)((rec.x >> 21) & BMASK);
            float xs = b2f((u32)xb[rec.x & SRCMASK]);
            float a0 = b2f(rec.y & 0xffffu);
            float a1 = b2f(rec.y >> 16);
            int* ap = &acc[l * 9];
#pragma unroll
            for (int j = 0; j < 9; j++) {
                float e  = fmaf(a0, sWe[2 * j], fmaf(a1, sWe[2 * j + 1], sbe[j]));
                float hh = fmaf(xs, sWx[j], sbx[j]);
                atomicAdd(&ap[j], fx(hh * e));
            }
        }
    }
    __syncthreads();

    // ---- node output pass: lin_out + relu + next-layer lin_x, bf16 pack ----
    int l = t;
    if (l < BSZ) {
        int n = b * BSZ + l;
        if (n < NNODES) {
            float av[9];
#pragma unroll
            for (int j = 0; j < 9; j++) av[j] = (float)acc[l * 9 + j] * FXINV;
            float o[9];
#pragma unroll
            for (int k = 0; k < 9; k++) {
                float v = sbo[k];
#pragma unroll
                for (int j = 0; j < 9; j++) v = fmaf(av[j], sWo[k * 9 + j], v);
                o[k] = fmaxf(v, 0.f);
            }
            u16 hv[9];
#pragma unroll
            for (int j = 0; j < 9; j++) {
                float v = sbxn[j];
#pragma unroll
                for (int k = 0; k < 9; k++) v = fmaf(o[k], sWxn[j * 9 + k], v);
                hv[j] = f2b(v);
            }
            uint4 q;
            q.x = (u32)hv[0] | ((u32)hv[1] << 16);
            q.y = (u32)hv[2] | ((u32)hv[3] << 16);
            q.z = (u32)hv[4] | ((u32)hv[5] << 16);
            q.w = (u32)hv[6] | ((u32)hv[7] << 16);
            ntst4(&hA[n], q);
            ntstw(&hB[n], hv[8]);
        }
    }
}

// ---- layers 2/3: bucket-pair cohort sweep, gather 16B+2B, fx LDS acc ----
// nt perm loads + nt output stores: the gather window owns the L2.

template <int OUTF, bool FUSE_NEXT>
__global__ __launch_bounds__(256) void k_eagg(
        const int* __restrict__ bstart, const uint2* __restrict__ perm,
        const uint4* __restrict__ hA, const u16* __restrict__ hB,
        const void* We, const void* be, const void* Wo, const void* bo,
        const void* Wxn, const void* bxn,
        uint4* __restrict__ oA, u16* __restrict__ oB,
        const int* __restrict__ flag) {
    __shared__ int acc[BSZ * 9];
    __shared__ float sWe[18], sbe[9], sWo[OUTF * 9], sbo[OUTF];
    __shared__ float sWxn[FUSE_NEXT ? 81 : 1], sbxn[FUSE_NEXT ? 9 : 1];
    int isf32 = *flag;
    int t = threadIdx.x;
    if (t < 18)       sWe[t] = ldw(We, t, isf32);
    if (t < 9)        sbe[t] = ldw(be, t, isf32);
    if (t < OUTF * 9) sWo[t] = ldw(Wo, t, isf32);
    if (t < OUTF)     sbo[t] = ldw(bo, t, isf32);
    if constexpr (FUSE_NEXT) {
        if (t < 81) sWxn[t] = ldw(Wxn, t, isf32);
        if (t < 9)  sbxn[t] = ldw(bxn, t, isf32);
    }
    __syncthreads();

#pragma unroll 1
    for (int half = 0; half < 2; half++) {
        int b = blockIdx.x * 2 + half;
        if (b >= NBUCK) break;            // uniform per block

        for (int i = t; i < BSZ * 9; i += 256) acc[i] = 0;
        __syncthreads();

        int r0 = bstart[b], r1 = bstart[b + 1];
        for (int i = r0 + t; i < r1; i += 256) {
            uint2 rec = ntld2(&perm[i]);
            int   s   = (int)(rec.x & SRCMASK);
            int   l   = (int)((rec.x >> 21) & BMASK);
            float a0  = b2f(rec.y & 0xffffu);
            float a1  = b2f(rec.y >> 16);
            uint4 qa  = hA[s];
            u32   qb  = (u32)hB[s];
            float ev[9];
#pragma unroll
            for (int j = 0; j < 9; j++)
                ev[j] = fmaf(a0, sWe[2 * j], fmaf(a1, sWe[2 * j + 1], sbe[j]));
            float h[9];
            h[0] = b2f(qa.x & 0xffffu); h[1] = b2f(qa.x >> 16);
            h[2] = b2f(qa.y & 0xffffu); h[3] = b2f(qa.y >> 16);
            h[4] = b2f(qa.z & 0xffffu); h[5] = b2f(qa.z >> 16);
            h[6] = b2f(qa.w & 0xffffu); h[7] = b2f(qa.w >> 16);
            h[8] = b2f(qb);
            int* ap = &acc[l * 9];
#pragma unroll
            for (int j = 0; j < 9; j++)
                atomicAdd(&ap[j], fx(h[j] * ev[j]));
        }
        __syncthreads();

        for (int l = t; l < BSZ; l += 256) {
            int n = b * BSZ + l;
            if (n >= NNODES) break;
            float av[9];
#pragma unroll
            for (int j = 0; j < 9; j++) av[j] = (float)acc[l * 9 + j] * FXINV;
            float o[OUTF];
#pragma unroll
            for (int k = 0; k < OUTF; k++) {
                float v = sbo[k];
#pragma unroll
                for (int j = 0; j < 9; j++) v = fmaf(av[j], sWo[k * 9 + j], v);
                o[k] = fmaxf(v, 0.f);
            }
            if constexpr (FUSE_NEXT) {
                u16 hv[9];
#pragma unroll
                for (int j = 0; j < 9; j++) {
                    float v = sbxn[j];
#pragma unroll
                    for (int k = 0; k < OUTF; k++) v = fmaf(o[k], sWxn[j * 9 + k], v);
                    hv[j] = f2b(v);
                }
                uint4 q;
                q.x = (u32)hv[0] | ((u32)hv[1] << 16);
                q.y = (u32)hv[2] | ((u32)hv[3] << 16);
                q.z = (u32)hv[4] | ((u32)hv[5] << 16);
                q.w = (u32)hv[6] | ((u32)hv[7] << 16);
                ntst4(&oA[n], q);
                ntstw(&oB[n], hv[8]);
            } else {
                uint2 q;
                q.x = (u32)f2b(o[0]) | ((u32)f2b(o[1]) << 16);
                q.y = (u32)f2b(o[2]) | ((u32)f2b(o[3]) << 16);
                ntst2(&((uint2*)oA)[n], q);   // f table: 8B/node
            }
        }
        __syncthreads();   // acc re-zeroed next half only after all reads
    }
}

// ---------------- head MLP + log_softmax ----------------

__global__ __launch_bounds__(256) void k_head(
        const u16* __restrict__ f,
        const void* W1, const void* b1, const void* W2, const void* b2,
        void* __restrict__ out, const int* __restrict__ flag) {
    __shared__ float sW1[192], sb1[8], sW2[32], sb2[4];
    int isf32 = *flag;
    int t = threadIdx.x;
    if (t < 192) sW1[t] = ldw(W1, t, isf32);
    if (t < 8)   sb1[t] = ldw(b1, t, isf32);
    if (t < 32)  sW2[t] = ldw(W2, t, isf32);
    if (t < 4)   sb2[t] = ldw(b2, t, isf32);
    __syncthreads();

    int tr = blockIdx.x * 256 + t;
    if (tr >= NTRACK) return;

    const uint4* fp = (const uint4*)(f + (size_t)tr * 24);
    uint4 A = fp[0], B = fp[1], C = fp[2];
    u32 w[12] = {A.x, A.y, A.z, A.w, B.x, B.y, B.z, B.w, C.x, C.y, C.z, C.w};
    float in[24];
#pragma unroll
    for (int i = 0; i < 12; i++) {
        in[2 * i]     = b2f(w[i] & 0xffffu);
        in[2 * i + 1] = b2f(w[i] >> 16);
    }

    float z1[8];
#pragma unroll
    for (int o = 0; o < 8; o++) {
        float v = sb1[o];
#pragma unroll
        for (int i = 0; i < 24; i++) v = fmaf(in[i], sW1[o * 24 + i], v);
        z1[o] = fmaxf(v, 0.f);
    }
    float z2[4];
#pragma unroll
    for (int c = 0; c < 4; c++) {
        float v = sb2[c];
#pragma unroll
        for (int o = 0; o < 8; o++) v = fmaf(z1[o], sW2[c * 8 + o], v);
        z2[c] = v;
    }
    float m = fmaxf(fmaxf(z2[0], z2[1]), fmaxf(z2[2], z2[3]));
    float s = 0.f;
#pragma unroll
    for (int c = 0; c < 4; c++) s += expf(z2[c] - m);
    float l = logf(s) + m;

    if (isf32) {
        float4 q; q.x = z2[0] - l; q.y = z2[1] - l; q.z = z2[2] - l; q.w = z2[3] - l;
        ((float4*)((float*)out + (size_t)tr * 4))[0] = q;
    } else {
        uint2 q;
        q.x = (u32)f2b(z2[0] - l) | ((u32)f2b(z2[1] - l) << 16);
        q.y = (u32)f2b(z2[2] - l) | ((u32)f2b(z2[3] - l) << 16);
        ((uint2*)((u16*)out + (size_t)tr * 4))[0] = q;
    }
}

// ---------------- host ----------------

extern "C" void kernel_launch(void* const* d_in, const int* in_sizes, int n_in,
                              void* d_out, int out_size, void* d_ws, size_t ws_size,
                              hipStream_t stream) {
    const void* X    = d_in[0];
    const int* eidx  = (const int*)d_in[1];
    const void* eattr= d_in[2];
    const void *WX1 = d_in[3],  *BX1 = d_in[4];
    const void *WE1 = d_in[5],  *BE1 = d_in[6];
    const void *WO1 = d_in[7],  *BO1 = d_in[8];
    const void *WX2 = d_in[9],  *BX2 = d_in[10];
    const void *WE2 = d_in[11], *BE2 = d_in[12];
    const void *WO2 = d_in[13], *BO2 = d_in[14];
    const void *WX3 = d_in[15], *BX3 = d_in[16];
    const void *WE3 = d_in[17], *BE3 = d_in[18];
    const void *WO3 = d_in[19], *BO3 = d_in[20];
    const void *W1  = d_in[21], *B1  = d_in[22];
    const void *W2  = d_in[23], *B2  = d_in[24];

    const int* src = eidx;
    const int* dst = eidx + NEDGES;

    // workspace layout (~189 MB)
    char* w = (char*)d_ws;
    size_t off = 0;
    auto take = [&](size_t bytes) -> void* {
        void* p = w + off;
        off += (bytes + 255) & ~(size_t)255;
        return p;
    };
    int*   flag   = (int*)take(256);
    int*   bstart = (int*)take((size_t)(NBUCK + 1) * 4);
    u16*   cnt    = (u16*)take((size_t)PBLK * NBUCK * 2);   // 17.2 MB
    u16*   offm   = (u16*)take((size_t)PBLK * NBUCK * 2);   // 17.2 MB
    u16*   st     = (u16*)take((size_t)NSEG * NBUCK * 2);   // 188 KB
    u32*   segb   = (u32*)take((size_t)NSEG * NBUCK * 4);   // 375 KB
    u16*   xb     = (u16*)take((size_t)NNODES * 2);         // 3 MB bf16 x
    uint2* perm   = (uint2*)take((size_t)NEDGES * 8);       // 96 MB exact
    uint4* hA2    = (uint4*)take((size_t)NNODES * 16);      // 24 MB
    u16*   hB2    = (u16*)take((size_t)NNODES * 2);         // 3 MB
    uint4* hA3    = (uint4*)take((size_t)NNODES * 16);      // 24 MB
    u16*   hB3    = (u16*)take((size_t)NNODES * 2);         // 3 MB
    u16*   f      = (u16*)hA2;  // layer-3 output (12 MB) reuses hA2 (dead by then)
    (void)ws_size; (void)n_in; (void)in_sizes; (void)out_size;

    const int NB = (NNODES + 255) / 256;
    const int TB = (NTRACK + 255) / 256;

    k_detect <<<1,    64,  0, stream>>>((const u16*)BX1, (const u16*)BE1, (const u16*)BO1,
                                        (const u16*)BX2, (const u16*)BE2, (const u16*)B1, flag);
    k_xcast  <<<NB,   256, 0, stream>>>(X, xb, flag);
    k_hist   <<<PBLK, 512, 0, stream>>>(dst, cnt);
    k_mscanA <<<NSEG * NTILE, 64, 0, stream>>>(cnt, offm, st);
    k_mscanB <<<1,    256, 0, stream>>>(st, bstart, segb);
    k_part   <<<PBLK, 512, 0, stream>>>(src, dst, eattr, cnt, offm, segb, perm, flag);

    k_srtagg1      <<<NBUCK, 512, 0, stream>>>(bstart, perm, xb,
                                               WX1, BX1, WE1, BE1, WO1, BO1, WX2, BX2,
                                               hA2, hB2, flag);
    k_eagg<9,true> <<<EGRID, 256, 0, stream>>>(bstart, perm, hA2, hB2,
                                               WE2, BE2, WO2, BO2, WX3, BX3,
                                               hA3, hB3, flag);
    k_eagg<4,false><<<EGRID, 256, 0, stream>>>(bstart, perm, hA3, hB3,
                                               WE3, BE3, WO3, BO3, WO3, BO3,
                                               (uint4*)f, (u16*)f, flag);
    k_head         <<<TB,    256, 0, stream>>>(f, W1, B1, W2, B2, d_out, flag);
}